// Round 4
// baseline (5668.890 us; speedup 1.0000x reference)
//
#include <hip/hip_runtime.h>
#include <cstdint>
#include <cstddef>

// ---------------------------------------------------------------------------
// E2E AttDot + 2-layer LSTM decoder + CE loss. B=32,T=400,D=E=1024,V=5000,L=100.
// R7: store-report grid barrier (1 per step, no RMW) + dependency flags for
//     B->C (64 z0 flags) and C->A (64 dq flags). gp1 split for phase C.
// ---------------------------------------------------------------------------

using short8  = __attribute__((ext_vector_type(8))) short;
using floatx4 = __attribute__((ext_vector_type(4))) float;
using floatx2 = __attribute__((ext_vector_type(2))) float;
typedef unsigned long long u64;

#define DEV __device__ __forceinline__

#if defined(__has_builtin)
#if __has_builtin(__builtin_amdgcn_cvt_pk_f32_fp8) && __has_builtin(__builtin_amdgcn_cvt_pk_fp8_f32)
#define HW_FP8 1
#endif
#endif

DEV float bf2f(unsigned int h) { union { unsigned int u; float f; } v; v.u = h << 16; return v.f; }
DEV unsigned short f2bf(float f) {
    union { float f; unsigned int u; } v; v.f = f;
    return (unsigned short)((v.u + 0x7fffu + ((v.u >> 16) & 1u)) >> 16);
}
DEV float sigm(float x) { return 1.0f / (1.0f + __expf(-x)); }

// ---- fp8 e4m3 software codecs (fallback + setup use)
DEV float fp8tof_sw(unsigned int b) {
    unsigned int s = (b & 0x80u) << 24;
    unsigned int em = b & 0x7fu;
    float vn = __uint_as_float(s | ((em + 960u) << 20));
    float vd = (float)(int)em * 0x1p-9f;
    vd = s ? -vd : vd;
    return (em >= 8u) ? vn : vd;
}
DEV unsigned int f2fp8_sw(float f) {
    unsigned int u = __float_as_uint(f);
    unsigned int s = (u >> 24) & 0x80u;
    unsigned int a = u & 0x7fffffffu;
    if (a >= 0x43e00000u) return s | 0x7eu;            // clamp +-448
    if (a < 0x3c800000u) {                              // denorm: m = rne(|f|*512)
        unsigned int mi = (unsigned int)(__uint_as_float(a) * 512.0f + 0.5f);
        return s | mi;
    }
    unsigned int lsb = (a >> 20) & 1u;
    a += 0x0007ffffu + lsb;
    unsigned int e = (a >> 23) - 120u;
    unsigned int m = (a >> 20) & 7u;
    return s | (e << 3) | m;
}
DEV void un4(unsigned int w, float* o) {
#ifdef HW_FP8
    floatx2 lo = __builtin_amdgcn_cvt_pk_f32_fp8((int)w, false);
    floatx2 hi = __builtin_amdgcn_cvt_pk_f32_fp8((int)w, true);
    o[0] = lo.x; o[1] = lo.y; o[2] = hi.x; o[3] = hi.y;
#else
    o[0] = fp8tof_sw(w & 0xffu); o[1] = fp8tof_sw((w >> 8) & 0xffu);
    o[2] = fp8tof_sw((w >> 16) & 0xffu); o[3] = fp8tof_sw(w >> 24);
#endif
}
DEV unsigned int pack4fp8(float a, float b, float c, float d) {
#ifdef HW_FP8
    int w = __builtin_amdgcn_cvt_pk_fp8_f32(a, b, 0, false);
    w = __builtin_amdgcn_cvt_pk_fp8_f32(c, d, w, true);
    return (unsigned int)w;
#else
    return f2fp8_sw(a) | (f2fp8_sw(b) << 8) | (f2fp8_sw(c) << 16) | (f2fp8_sw(d) << 24);
#endif
}
DEV unsigned char f2fp8_1(float v) {
#ifdef HW_FP8
    return (unsigned char)((unsigned int)__builtin_amdgcn_cvt_pk_fp8_f32(v, v, 0, false) & 0xffu);
#else
    return (unsigned char)f2fp8_sw(v);
#endif
}
DEV u64 pack4bf16(float a, float b, float c, float d) {
    union { unsigned int w[2]; u64 q; } u;
    u.w[0] = (unsigned int)f2bf(a) | ((unsigned int)f2bf(b) << 16);
    u.w[1] = (unsigned int)f2bf(c) | ((unsigned int)f2bf(d) << 16);
    return u.q;
}

// relaxed agent-scope accessors (per-access coherence, no cache-wide inv)
DEV u64  lda64(const void* p) { return __hip_atomic_load((const u64*)p, __ATOMIC_RELAXED, __HIP_MEMORY_SCOPE_AGENT); }
DEV void sta64(void* p, u64 v) { __hip_atomic_store((u64*)p, v, __ATOMIC_RELAXED, __HIP_MEMORY_SCOPE_AGENT); }
DEV void sta32(void* p, unsigned int v) { __hip_atomic_store((unsigned int*)p, v, __ATOMIC_RELAXED, __HIP_MEMORY_SCOPE_AGENT); }
DEV int  lda32i(const int* p) { return __hip_atomic_load(p, __ATOMIC_RELAXED, __HIP_MEMORY_SCOPE_AGENT); }
DEV float ldaf(const void* p) { return __hip_atomic_load((const float*)p, __ATOMIC_RELAXED, __HIP_MEMORY_SCOPE_AGENT); }
DEV void staf(void* p, float v) { __hip_atomic_store((float*)p, v, __ATOMIC_RELAXED, __HIP_MEMORY_SCOPE_AGENT); }
DEV int  arrive(int* p) { return __hip_atomic_fetch_add(p, 1, __ATOMIC_RELAXED, __HIP_MEMORY_SCOPE_AGENT); }

// Counter layout (ints):
//   cntA   : base + b*32          (32 padded counters, 8 arrivals/step)
//   cnt0   : base + 1024 + dc*32  (64 padded counters, 4 arrivals/step)
//   cnt1   : base + 3072 + dc*32  (64 padded counters, 4 arrivals/step)
//   bslots : base + 5120 .. +256  (store-report barrier, 1 slot/block)
//   zslot  : base + 5376 .. +64   (z0-ready flags, 1/dc)
//   dqslot : base + 5440 .. +64   (dq-ready flags, 1/dc)

// ---------------------------------------------------------------- utilities
__global__ __launch_bounds__(256) void k_zero(unsigned int* p, int n) {
    int i = blockIdx.x * 256 + threadIdx.x;
    if (i < n) p[i] = 0u;
}

__global__ __launch_bounds__(256) void k_conv4(const float* __restrict__ in,
                                               unsigned short* __restrict__ out, int n4) {
    int i = blockIdx.x * 256 + threadIdx.x;
    if (i >= n4) return;
    float4 v = ((const float4*)in)[i];
    unsigned int w0 = (unsigned int)f2bf(v.x) | ((unsigned int)f2bf(v.y) << 16);
    unsigned int w1 = (unsigned int)f2bf(v.z) | ((unsigned int)f2bf(v.w) << 16);
    ((uint2*)(void*)out)[i] = make_uint2(w0, w1);
}

// hs: f32 -> bf16 (for pre-GEMM) + fp8 (for attention)
__global__ __launch_bounds__(256) void k_convhs(const float* __restrict__ in,
                                                unsigned short* __restrict__ obf,
                                                unsigned int* __restrict__ o8, int n4) {
    int i = blockIdx.x * 256 + threadIdx.x;
    if (i >= n4) return;
    float4 v = ((const float4*)in)[i];
    unsigned int w0 = (unsigned int)f2bf(v.x) | ((unsigned int)f2bf(v.y) << 16);
    unsigned int w1 = (unsigned int)f2bf(v.z) | ((unsigned int)f2bf(v.w) << 16);
    ((uint2*)(void*)obf)[i] = make_uint2(w0, w1);
    o8[i] = pack4fp8(v.x, v.y, v.z, v.w);
}

__global__ __launch_bounds__(256) void k_conv8(const float* __restrict__ in,
                                               unsigned int* __restrict__ o8, int n4) {
    int i = blockIdx.x * 256 + threadIdx.x;
    if (i >= n4) return;
    float4 v = ((const float4*)in)[i];
    o8[i] = pack4fp8(v.x, v.y, v.z, v.w);
}

// fp8 [N][Ka+Kb] from f32 A[N][Ka], B[N][Kb] (Ka,Kb multiples of 4)
__global__ __launch_bounds__(256) void k_cat2_8(const float* __restrict__ A, const float* __restrict__ Bsrc,
                                                unsigned int* __restrict__ dst, int N, int Ka, int Kb) {
    int idx = blockIdx.x * 256 + threadIdx.x;
    int K4 = (Ka + Kb) >> 2;
    if (idx >= N * K4) return;
    int n = idx / K4, k = (idx - n * K4) * 4;
    const float* src = (k < Ka) ? (A + (size_t)n * Ka + k) : (Bsrc + (size_t)n * Kb + (k - Ka));
    dst[idx] = pack4fp8(src[0], src[1], src[2], src[3]);
}

__global__ __launch_bounds__(256) void k_woutpad(const float* __restrict__ W, unsigned short* __restrict__ dst) {
    int idx = blockIdx.x * 256 + threadIdx.x;
    if (idx >= 5120 * 2048) return;
    int n = idx >> 11, k = idx & 2047;
    dst[idx] = (n < 5000) ? f2bf(W[(size_t)n * 2048 + k]) : (unsigned short)0;
}

__global__ __launch_bounds__(256) void k_bsum(const float* a0, const float* b0, const float* a1, const float* b1,
                                              float* s0, float* s1) {
    int i = blockIdx.x * 256 + threadIdx.x;
    if (i < 4096) s0[i] = a0[i] + b0[i];
    else if (i < 8192) s1[i - 4096] = a1[i - 4096] + b1[i - 4096];
}

// eys fp8 [l][b][1024]
__global__ __launch_bounds__(256) void k_eys8(const float* __restrict__ embed, const int* __restrict__ ys_pad,
                                              unsigned int* __restrict__ eys8) {
    int idx = blockIdx.x * 256 + threadIdx.x;
    if (idx >= 3232 * 256) return;
    int rb = idx >> 8, c4 = idx & 255;
    int l = rb >> 5, b = rb & 31;
    int tok = (l == 0) ? 4999 : ys_pad[b * 100 + (l - 1)];
    const float* e = embed + (size_t)tok * 1024 + c4 * 4;
    eys8[idx] = pack4fp8(e[0], e[1], e[2], e[3]);
}

// dq init: z0=0 -> dq = tanh(bdec)
__global__ __launch_bounds__(256) void k_dq0(const float* __restrict__ bdec, unsigned short* __restrict__ dq) {
    int idx = blockIdx.x * 256 + threadIdx.x;
    if (idx >= 32768) return;
    dq[idx] = f2bf(tanhf(bdec[idx & 1023]));
}

// --------------------------------------------------- big 128x128 MFMA GEMM
// mode0: o8 = fp8(tanh(C+bias));  mode1: of32 = C
__global__ __launch_bounds__(256) void k_gemm128(
    const unsigned short* __restrict__ A, const unsigned short* __restrict__ B,
    int K, int N, const float* __restrict__ bias,
    unsigned char* __restrict__ o8, float* __restrict__ of32, int mode) {
    __shared__ uint4 Ab[512];
    __shared__ uint4 Bb[512];
    const int tid = threadIdx.x;
    const int lane = tid & 63, wave = tid >> 6;
    const int r = lane & 15, q = lane >> 4;
    const int wm = wave >> 1, wn = wave & 1;
    const size_t am0 = (size_t)blockIdx.y * 128;
    const size_t bn0 = (size_t)blockIdx.x * 128;
    floatx4 zf = {0.f, 0.f, 0.f, 0.f};
    floatx4 acc[4][4];
#pragma unroll
    for (int i = 0; i < 4; i++)
#pragma unroll
        for (int j = 0; j < 4; j++) acc[i][j] = zf;

    for (int k0 = 0; k0 < K; k0 += 32) {
        __syncthreads();
#pragma unroll
        for (int i = 0; i < 2; ++i) {
            int idx = i * 256 + tid;
            int qq = idx & 3, rr = idx >> 2;
            int slot = (rr >> 4) * 64 + ((qq << 4) | (rr & 15));
            Ab[slot] = *(const uint4*)(const void*)(A + (am0 + rr) * K + k0 + qq * 8);
            Bb[slot] = *(const uint4*)(const void*)(B + (bn0 + rr) * K + k0 + qq * 8);
        }
        __syncthreads();
        short8 af[4], bf[4];
#pragma unroll
        for (int t = 0; t < 4; t++) af[t] = *(const short8*)(const void*)&Ab[(wm * 4 + t) * 64 + lane];
#pragma unroll
        for (int t = 0; t < 4; t++) bf[t] = *(const short8*)(const void*)&Bb[(wn * 4 + t) * 64 + lane];
#pragma unroll
        for (int tm = 0; tm < 4; tm++)
#pragma unroll
            for (int tn = 0; tn < 4; tn++)
                acc[tm][tn] = __builtin_amdgcn_mfma_f32_16x16x32_bf16(af[tm], bf[tn], acc[tm][tn], 0, 0, 0);
    }
#pragma unroll
    for (int tm = 0; tm < 4; tm++) {
#pragma unroll
        for (int tn = 0; tn < 4; tn++) {
            int col = (int)bn0 + wn * 64 + tn * 16 + r;
#pragma unroll
            for (int reg = 0; reg < 4; ++reg) {
                size_t row = am0 + wm * 64 + tm * 16 + q * 4 + reg;
                float v = acc[tm][tn][reg];
                if (mode == 0) {
                    v = tanhf(v + bias[col]);
                    o8[row * (size_t)N + col] = f2fp8_1(v);
                } else {
                    of32[row * (size_t)N + col] = v;
                }
            }
        }
    }
}

// ------------------------------------------------- persistent scan kernel
struct SArgs {
    const unsigned char* pre8;   // [12800][1024] fp8
    const unsigned char* hs8;    // [12800][1024] fp8
    const unsigned char* eys8;   // [3232][1024] fp8
    const unsigned char* wc0;    // [4096][3072] fp8
    const unsigned char* wc1;    // [4096][2048] fp8
    const unsigned char* wdec;   // [1024][1024] fp8
    unsigned short* dq;          // [32][1024] bf16
    unsigned char* x0r;          // [2][32][3072] fp8
    unsigned char* x1r;          // [2][32][2048] fp8
    unsigned short* zall;        // [3328][2048] bf16
    const float* bdec; const float* bs0; const float* bs1;
    float* c0; float* c1;
    float* gp;                   // [4][4096][32] f32 (cell0)
    float* gp1;                  // [4][4096][32] f32 (cell1)
    float* part; float* lmaxg; float* lsumg;
    int* cntA; int* cnt0; int* cnt1;
    int* bslots; int* zslot; int* dqslot;
    const int* hlens;
};

// store-report grid barrier: each block stores ep to its own slot (no RMW);
// wave 0 of every block polls all 256 slots (4 coalesced loads/lane).
DEV void gbar2(int* slots, int ep) {
    __builtin_amdgcn_s_waitcnt(0);
    __syncthreads();
    if (threadIdx.x == 0) sta32(slots + blockIdx.x, (unsigned int)ep);
    if (threadIdx.x < 64) {
        for (;;) {
            int a0 = lda32i(slots + threadIdx.x);
            int a1 = lda32i(slots + 64 + threadIdx.x);
            int a2 = lda32i(slots + 128 + threadIdx.x);
            int a3 = lda32i(slots + 192 + threadIdx.x);
            int m = (a0 >= ep) & (a1 >= ep) & (a2 >= ep) & (a3 >= ep);
            if (__all(m)) break;
            __builtin_amdgcn_s_sleep(1);
        }
    }
    __syncthreads();
}

// poll 64 producer flags (wave 0; 1 slot/lane)
DEV void poll64(int* slots, int ep) {
    if (threadIdx.x < 64) {
        for (;;) {
            int v = lda32i(slots + threadIdx.x);
            if (__all(v >= ep)) break;
            __builtin_amdgcn_s_sleep(1);
        }
    }
    __syncthreads();
}

__global__ __launch_bounds__(256, 1) void k_scan(SArgs a) {
    const int blk = blockIdx.x, tid = threadIdx.x;
    const int lane = tid & 63, wave = tid >> 6;
    const int b = blk >> 3, ch = blk & 7;       // attention role
    const int dc = blk >> 2, kc = blk & 3;      // cell role
    const int r = lane & 15, q = lane >> 4;
    const int hlen = a.hlens[b];

    __shared__ __align__(16) unsigned char preS[51200];  // 50x1024 fp8 (whole slice)
    __shared__ __align__(16) unsigned char hsS[51200];   // 50x1024 fp8 (whole slice)
    __shared__ __align__(16) unsigned char AS[24832];    // staging (B:32x776, C:32x520, A:dq 2KB)
    __shared__ float dqS[32][16];
    __shared__ float e4[50][4];
    __shared__ float es[52];
    __shared__ float ps[52];
    __shared__ int lastf;

    // one-time LDS fill: pre8/hs8 [b][ch*50 .. +49][:]
    {
        const u64* psrc = (const u64*)(const void*)(a.pre8 + (size_t)(b * 400 + ch * 50) * 1024);
        const u64* hsrc = (const u64*)(const void*)(a.hs8 + (size_t)(b * 400 + ch * 50) * 1024);
        u64* pd = (u64*)(void*)preS;
        u64* hd = (u64*)(void*)hsS;
        for (int i = tid; i < 6400; i += 256) { pd[i] = psrc[i]; hd[i] = hsrc[i]; }
    }
    __syncthreads();

    for (int l = 0; l < 101; ++l) {
        unsigned char* X0l = a.x0r + (size_t)(l & 1) * 98304;
        unsigned char* X0n = a.x0r + (size_t)((l + 1) & 1) * 98304;
        unsigned char* X1l = a.x1r + (size_t)(l & 1) * 65536;
        unsigned char* X1n = a.x1r + (size_t)((l + 1) & 1) * 65536;

        // ================= phase A: attention =================
        {
            if (l > 0) poll64(a.dqslot, l);   // dq(l) ready (written in C(l-1))
            // stage dq[b] (2 KB bf16) into AS once per block
            ((u64*)(void*)AS)[tid] = (tid < 256) ? lda64((const char*)(const void*)(a.dq + b * 1024) + tid * 8) : 0;
            __syncthreads();
            float dqf[16];
            {
                const unsigned int* dw = (const unsigned int*)(const void*)AS + lane * 8;
#pragma unroll
                for (int i = 0; i < 8; ++i) {
                    unsigned int w = dw[i];
                    dqf[2 * i] = bf2f(w & 0xffffu);
                    dqf[2 * i + 1] = bf2f(w >> 16);
                }
            }
            for (int tl = wave; tl < 50; tl += 4) {
                uint4 v = *(const uint4*)(const void*)(preS + tl * 1024 + lane * 16);
                float x[16];
                un4(v.x, x); un4(v.y, x + 4); un4(v.z, x + 8); un4(v.w, x + 12);
                float s = 0.f;
#pragma unroll
                for (int i = 0; i < 16; ++i) s += x[i] * dqf[i];
                s += __shfl_xor(s, 1, 64);
                s += __shfl_xor(s, 2, 64);
                s += __shfl_xor(s, 4, 64);
                s += __shfl_xor(s, 8, 64);
                if ((lane & 15) == 0) e4[tl][lane >> 4] = s;
            }
            __syncthreads();
            if (tid < 50) {
                float4 v = *(const float4*)(const void*)e4[tid];
                float e = v.x + v.y + v.z + v.w;
                int t = ch * 50 + tid;
                es[tid] = (t < hlen) ? 2.0f * e : -1e30f;
            }
            __syncthreads();
            float lmax = -1e30f;
#pragma unroll
            for (int i = 0; i < 50; ++i) lmax = fmaxf(lmax, es[i]);
            if (tid < 50) ps[tid] = (es[tid] > -5e29f) ? __expf(es[tid] - lmax) : 0.f;
            __syncthreads();
            if (tid == 0) {
                float ssum = 0.f;
                for (int i = 0; i < 50; ++i) ssum += ps[i];
                staf(a.lmaxg + b * 8 + ch, lmax);
                staf(a.lsumg + b * 8 + ch, ssum);
            }
            const int c = tid * 4;
            float a0 = 0.f, a1 = 0.f, a2 = 0.f, a3 = 0.f;
            for (int tl = 0; tl < 50; ++tl) {
                float p = ps[tl];
                unsigned int h = *(const unsigned int*)(const void*)(hsS + tl * 1024 + c);
                float x[4];
                un4(h, x);
                a0 += p * x[0]; a1 += p * x[1]; a2 += p * x[2]; a3 += p * x[3];
            }
            {
                float* pb = a.part + ((size_t)(b * 8 + ch)) * 1024 + c;
                union { float f[2]; u64 q; } p0, p1;
                p0.f[0] = a0; p0.f[1] = a1; p1.f[0] = a2; p1.f[1] = a3;
                sta64(pb, p0.q); sta64(pb + 2, p1.q);
            }
            __builtin_amdgcn_s_waitcnt(0);
            __syncthreads();
            if (tid == 0) lastf = (arrive(a.cntA + b * 32) == 8 * l + 7);
            __syncthreads();
            if (lastf) {
                float lm[8], ls[8];
#pragma unroll
                for (int i = 0; i < 8; ++i) {
                    lm[i] = ldaf(a.lmaxg + b * 8 + i);
                    ls[i] = ldaf(a.lsumg + b * 8 + i);
                }
                float gm = -1e30f;
#pragma unroll
                for (int i = 0; i < 8; ++i) gm = fmaxf(gm, lm[i]);
                float Zs = 0.f;
#pragma unroll
                for (int i = 0; i < 8; ++i) Zs += ls[i] * __expf(lm[i] - gm);
                const float inv = 1.0f / Zs;
                float o0 = 0.f, o1 = 0.f, o2 = 0.f, o3 = 0.f;
#pragma unroll
                for (int i = 0; i < 8; ++i) {
                    float coef = __expf(lm[i] - gm) * inv;
                    const float* qp = a.part + ((size_t)(b * 8 + i)) * 1024 + c;
                    union { u64 q; float f[2]; } u0, u1;
                    u0.q = lda64(qp); u1.q = lda64(qp + 2);
                    o0 += coef * u0.f[0]; o1 += coef * u0.f[1];
                    o2 += coef * u1.f[0]; o3 += coef * u1.f[1];
                }
                sta32(X0l + (size_t)b * 3072 + 1024 + c, pack4fp8(o0, o1, o2, o3));
                sta64(a.zall + ((size_t)(l * 32 + b)) * 2048 + 1024 + c, pack4bf16(o0, o1, o2, o3));
                unsigned int ey = *(const unsigned int*)(const void*)(a.eys8 + ((size_t)(l * 32 + b)) * 1024 + c);
                sta32(X0l + (size_t)b * 3072 + c, ey);
            }
        }
        gbar2(a.bslots, l + 1);   // the single grid barrier per step

        // ================= phase B: LSTM cell 0 =================
        {
            for (int i = tid; i < 3072; i += 256) {   // 32 rows x 96 u64 (768 B)
                int row = i / 96, col = i - row * 96;
                ((u64*)(void*)AS)[row * 97 + col] =
                    lda64((const char*)X0l + (size_t)row * 3072 + kc * 768 + col * 8);
            }
            __syncthreads();
            const unsigned char* Br = a.wc0 + (size_t)(wave * 1024 + dc * 16 + r) * 3072 + kc * 768 + q * 8;
            const unsigned char* A0 = AS + r * 776 + q * 8;
            const unsigned char* A1 = A0 + 16 * 776;
            floatx4 acc0 = {0.f, 0.f, 0.f, 0.f}, acc1 = acc0;
#pragma unroll 4
            for (int kk = 0; kk < 768; kk += 32) {
                long long bfr = *(const long long*)(const void*)(Br + kk);
                long long a0 = *(const long long*)(const void*)(A0 + kk);
                long long a1 = *(const long long*)(const void*)(A1 + kk);
                acc0 = __builtin_amdgcn_mfma_f32_16x16x32_fp8_fp8(a0, bfr, acc0, 0, 0, 0);
                acc1 = __builtin_amdgcn_mfma_f32_16x16x32_fp8_fp8(a1, bfr, acc1, 0, 0, 0);
            }
            const int n = wave * 1024 + dc * 16 + r;
            float* gb = a.gp + ((size_t)kc * 4096 + n) * 32;
            {
                union { floatx4 v; u64 q2[2]; } u0, u1;
                u0.v = acc0; u1.v = acc1;
                sta64(gb + q * 4, u0.q2[0]);      sta64(gb + q * 4 + 2, u0.q2[1]);
                sta64(gb + 16 + q * 4, u1.q2[0]); sta64(gb + 16 + q * 4 + 2, u1.q2[1]);
            }
            __builtin_amdgcn_s_waitcnt(0);
            __syncthreads();
            if (tid == 0) lastf = (arrive(a.cnt0 + dc * 32) == 4 * l + 3);
            __syncthreads();
            if (lastf && tid < 128) {
                const int bb = tid & 31, dg = tid >> 5;
                const int d0 = dc * 16 + dg * 4;
                float z[4];
#pragma unroll
                for (int j = 0; j < 4; ++j) {
                    const int d = d0 + j;
                    float g0 = a.bs0[d], g1 = a.bs0[1024 + d], g2 = a.bs0[2048 + d], g3 = a.bs0[3072 + d];
#pragma unroll
                    for (int kcc = 0; kcc < 4; ++kcc) {
                        const float* gpp = a.gp + (size_t)kcc * 131072;
                        g0 += ldaf(gpp + (size_t)d * 32 + bb);
                        g1 += ldaf(gpp + (size_t)(1024 + d) * 32 + bb);
                        g2 += ldaf(gpp + (size_t)(2048 + d) * 32 + bb);
                        g3 += ldaf(gpp + (size_t)(3072 + d) * 32 + bb);
                    }
                    float cn = sigm(g1) * ldaf(a.c0 + d * 32 + bb) + sigm(g0) * tanhf(g2);
                    staf(a.c0 + d * 32 + bb, cn);
                    z[j] = sigm(g3) * tanhf(cn);
                }
                unsigned int zp = pack4fp8(z[0], z[1], z[2], z[3]);
                sta32(X1l + bb * 2048 + d0, zp);
                sta32(X0n + (size_t)bb * 3072 + 2048 + d0, zp);
            }
            if (lastf) __builtin_amdgcn_s_waitcnt(0);
            __syncthreads();
            if (lastf && tid == 0) sta32(a.zslot + dc, (unsigned int)(l + 1));
        }

        // ================= phase C: LSTM cell 1 + next dq =================
        {
            if (kc < 2) poll64(a.zslot, l + 1);   // z0(l) ready (kc>=2 reads only z1(l-1))
            for (int i = tid; i < 2048; i += 256) {   // 32 rows x 64 u64 (512 B)
                int row = i >> 6, col = i & 63;
                ((u64*)(void*)AS)[row * 65 + col] =
                    lda64((const char*)X1l + (size_t)row * 2048 + kc * 512 + col * 8);
            }
            __syncthreads();
            const unsigned char* Br = a.wc1 + (size_t)(wave * 1024 + dc * 16 + r) * 2048 + kc * 512 + q * 8;
            const unsigned char* A0 = AS + r * 520 + q * 8;
            const unsigned char* A1 = A0 + 16 * 520;
            floatx4 acc0 = {0.f, 0.f, 0.f, 0.f}, acc1 = acc0;
#pragma unroll 4
            for (int kk = 0; kk < 512; kk += 32) {
                long long bfr = *(const long long*)(const void*)(Br + kk);
                long long a0 = *(const long long*)(const void*)(A0 + kk);
                long long a1 = *(const long long*)(const void*)(A1 + kk);
                acc0 = __builtin_amdgcn_mfma_f32_16x16x32_fp8_fp8(a0, bfr, acc0, 0, 0, 0);
                acc1 = __builtin_amdgcn_mfma_f32_16x16x32_fp8_fp8(a1, bfr, acc1, 0, 0, 0);
            }
            const int n = wave * 1024 + dc * 16 + r;
            float* gb = a.gp1 + ((size_t)kc * 4096 + n) * 32;
            {
                union { floatx4 v; u64 q2[2]; } u0, u1;
                u0.v = acc0; u1.v = acc1;
                sta64(gb + q * 4, u0.q2[0]);      sta64(gb + q * 4 + 2, u0.q2[1]);
                sta64(gb + 16 + q * 4, u1.q2[0]); sta64(gb + 16 + q * 4 + 2, u1.q2[1]);
            }
            // next-step dq on kc==0 blocks, waves 0-1 (z0 from phase B)
            if (kc == 0 && wave < 2) {
                floatx4 acc = {0.f, 0.f, 0.f, 0.f};
                const unsigned char* Brow = a.wdec + (size_t)(dc * 16 + r) * 1024 + q * 8;
                const char* Arow = (const char*)X1l + (size_t)(wave * 16 + r) * 2048 + q * 8;
#pragma unroll 4
                for (int k0 = 0; k0 < 1024; k0 += 32) {
                    long long bfr = *(const long long*)(const void*)(Brow + k0);
                    long long afr = (long long)lda64(Arow + k0);
                    acc = __builtin_amdgcn_mfma_f32_16x16x32_fp8_fp8(afr, bfr, acc, 0, 0, 0);
                }
                const int nn = dc * 16 + r;
#pragma unroll
                for (int reg = 0; reg < 4; ++reg)
                    dqS[wave * 16 + q * 4 + reg][r] = tanhf(acc[reg] + a.bdec[nn]);
            }
            __builtin_amdgcn_s_waitcnt(0);
            __syncthreads();
            if (tid == 0) lastf = (arrive(a.cnt1 + dc * 32) == 4 * l + 3);
            __syncthreads();
            if (kc == 0 && tid < 128) {
                const int m = tid >> 2, j = tid & 3;
                sta64(a.dq + (size_t)m * 1024 + dc * 16 + j * 4,
                      pack4bf16(dqS[m][j * 4], dqS[m][j * 4 + 1], dqS[m][j * 4 + 2], dqS[m][j * 4 + 3]));
            }
            if (kc == 0) __builtin_amdgcn_s_waitcnt(0);
            __syncthreads();
            if (kc == 0 && tid == 0) sta32(a.dqslot + dc, (unsigned int)(l + 1));
            if (lastf && tid < 128) {
                const int bb = tid & 31, dg = tid >> 5;
                const int d0 = dc * 16 + dg * 4;
                float z[4];
#pragma unroll
                for (int j = 0; j < 4; ++j) {
                    const int d = d0 + j;
                    float g0 = a.bs1[d], g1 = a.bs1[1024 + d], g2 = a.bs1[2048 + d], g3 = a.bs1[3072 + d];
#pragma unroll
                    for (int kcc = 0; kcc < 4; ++kcc) {
                        const float* gpp = a.gp1 + (size_t)kcc * 131072;
                        g0 += ldaf(gpp + (size_t)d * 32 + bb);
                        g1 += ldaf(gpp + (size_t)(1024 + d) * 32 + bb);
                        g2 += ldaf(gpp + (size_t)(2048 + d) * 32 + bb);
                        g3 += ldaf(gpp + (size_t)(3072 + d) * 32 + bb);
                    }
                    float cn = sigm(g1) * ldaf(a.c1 + d * 32 + bb) + sigm(g0) * tanhf(g2);
                    staf(a.c1 + d * 32 + bb, cn);
                    z[j] = sigm(g3) * tanhf(cn);
                }
                sta32(X1n + bb * 2048 + 1024 + d0, pack4fp8(z[0], z[1], z[2], z[3]));
                sta64(a.zall + ((size_t)(l * 32 + bb)) * 2048 + d0, pack4bf16(z[0], z[1], z[2], z[3]));
            }
        }
    }
}

// ----------------------------------------------------------- CE reduction
__global__ __launch_bounds__(256) void k_ce(const float* __restrict__ y, const float* __restrict__ bout,
                                            const int* __restrict__ ys_pad, float* __restrict__ out) {
    const int rrow = blockIdx.x;
    const int l = rrow >> 5, b = rrow & 31;
    const float* yp = y + (size_t)rrow * 5120;
    const int tid = threadIdx.x;
    __shared__ float red[256];
    float m = -1e30f;
    for (int c = tid; c < 5000; c += 256) m = fmaxf(m, yp[c] + bout[c]);
    red[tid] = m; __syncthreads();
    for (int s = 128; s; s >>= 1) { if (tid < s) red[tid] = fmaxf(red[tid], red[tid + s]); __syncthreads(); }
    const float gmax = red[0]; __syncthreads();
    float ss = 0.f;
    for (int c = tid; c < 5000; c += 256) ss += __expf(yp[c] + bout[c] - gmax);
    red[tid] = ss; __syncthreads();
    for (int s = 128; s; s >>= 1) { if (tid < s) red[tid] += red[tid + s]; __syncthreads(); }
    if (tid == 0) {
        const int tgt = (l < 100) ? ys_pad[b * 100 + l] : 4999;
        const float lt = yp[tgt] + bout[tgt];
        const float ce = logf(red[0]) + gmax - lt;
        atomicAdd(out, ce * (100.0f / 3232.0f));
    }
}

// ---------------------------------------------------------------------------
extern "C" void kernel_launch(void* const* d_in, const int* in_sizes, int n_in,
                              void* d_out, int out_size, void* d_ws, size_t ws_size,
                              hipStream_t stream) {
    const float* hs_pad = (const float*)d_in[0];
    const float* embed  = (const float*)d_in[1];
    const float* Wenc   = (const float*)d_in[2];
    const float* benc   = (const float*)d_in[3];
    const float* Wdec   = (const float*)d_in[4];
    const float* bdec   = (const float*)d_in[5];
    const float* W_ih0  = (const float*)d_in[6];
    const float* W_hh0  = (const float*)d_in[7];
    const float* b_ih0  = (const float*)d_in[8];
    const float* b_hh0  = (const float*)d_in[9];
    const float* W_ih1  = (const float*)d_in[10];
    const float* W_hh1  = (const float*)d_in[11];
    const float* b_ih1  = (const float*)d_in[12];
    const float* b_hh1  = (const float*)d_in[13];
    const float* Wout   = (const float*)d_in[14];
    const float* bout   = (const float*)d_in[15];
    const int*   hlens  = (const int*)d_in[16];
    const int*   ys_pad = (const int*)d_in[17];
    float* out = (float*)d_out;
    uint8_t* ws = (uint8_t*)d_ws;

    // layout: dead-by-final-GEMM buffers first (Y f32 68.2MB aliases them)
    constexpr size_t OFF_HS    = 0;                        // 26,214,400 bf16 hs (dead after pre-GEMM; GP1 reuses)
    constexpr size_t OFF_PRE8  = OFF_HS    + 26214400;     // 13,107,200
    constexpr size_t OFF_HS8   = OFF_PRE8  + 13107200;     // 13,107,200
    constexpr size_t OFF_WC08  = OFF_HS8   + 13107200;     // 12,582,912
    constexpr size_t OFF_WC18  = OFF_WC08  + 12582912;     //  8,388,608
    constexpr size_t OFF_WDEC8 = OFF_WC18  + 8388608;      //  1,048,576
    constexpr size_t OFF_WENC  = OFF_WDEC8 + 1048576;      //  2,097,152 bf16
    constexpr size_t OFF_EYS8  = OFF_WENC  + 2097152;      //  3,309,568
    constexpr size_t OFF_ZALL  = OFF_EYS8  + 3309568;      // 13,631,488 bf16
    constexpr size_t OFF_WOUT  = OFF_ZALL  + 13631488;     // 20,971,520 bf16
    constexpr size_t OFF_GP    = OFF_WOUT  + 20971520;     //  2,097,152 f32
    constexpr size_t OFF_PART  = OFF_GP    + 2097152;      //  1,048,576
    constexpr size_t OFF_LMAX  = OFF_PART  + 1048576;      //  1,024
    constexpr size_t OFF_LSUM  = OFF_LMAX  + 1024;         //  1,024
    constexpr size_t OFF_DQ    = OFF_LSUM  + 1024;         //  65,536
    constexpr size_t OFF_X0R   = OFF_DQ    + 65536;        //  196,608
    constexpr size_t OFF_X1R   = OFF_X0R   + 196608;       //  131,072
    constexpr size_t OFF_C0    = OFF_X1R   + 131072;       //  131,072
    constexpr size_t OFF_C1    = OFF_C0    + 131072;       //  131,072
    constexpr size_t OFF_BS0   = OFF_C1    + 131072;       //  16,384
    constexpr size_t OFF_BS1   = OFF_BS0   + 16384;        //  16,384
    constexpr size_t OFF_Y     = 0;
    // counters live in ZALL pad rows (rows 3232..3327, zeroed each call,
    // never written by the scan; read only into unused Y rows by final GEMM)
    constexpr size_t OFF_CNT   = OFF_ZALL + (size_t)3232 * 2048 * 2;
    // gp1 reuses the dead HS region (offset 0), overwritten later by Y
    constexpr size_t OFF_GP1   = 0;

    unsigned short* HS    = (unsigned short*)(ws + OFF_HS);
    unsigned char*  PRE8  = (unsigned char*)(ws + OFF_PRE8);
    unsigned char*  HS8   = (unsigned char*)(ws + OFF_HS8);
    unsigned char*  WC08  = (unsigned char*)(ws + OFF_WC08);
    unsigned char*  WC18  = (unsigned char*)(ws + OFF_WC18);
    unsigned char*  WDEC8 = (unsigned char*)(ws + OFF_WDEC8);
    unsigned short* WENC  = (unsigned short*)(ws + OFF_WENC);
    unsigned char*  EYS8  = (unsigned char*)(ws + OFF_EYS8);
    unsigned short* ZALL  = (unsigned short*)(ws + OFF_ZALL);
    unsigned short* WOUTP = (unsigned short*)(ws + OFF_WOUT);
    float* GP    = (float*)(ws + OFF_GP);
    float* GP1   = (float*)(ws + OFF_GP1);
    float* PART  = (float*)(ws + OFF_PART);
    float* LMAX  = (float*)(ws + OFF_LMAX);
    float* LSUM  = (float*)(ws + OFF_LSUM);
    unsigned short* DQ  = (unsigned short*)(ws + OFF_DQ);
    unsigned char*  X0R = (unsigned char*)(ws + OFF_X0R);
    unsigned char*  X1R = (unsigned char*)(ws + OFF_X1R);
    float* C0   = (float*)(ws + OFF_C0);
    float* C1   = (float*)(ws + OFF_C1);
    float* BS0  = (float*)(ws + OFF_BS0);
    float* BS1  = (float*)(ws + OFF_BS1);
    int* CNT    = (int*)(ws + OFF_CNT);
    float* Y = (float*)(ws + OFF_Y);

    auto Zr = [&](void* p, int n_u32) {
        k_zero<<<dim3((n_u32 + 255) / 256), dim3(256), 0, stream>>>((unsigned int*)p, n_u32);
    };

    // ---- setup (re-done every call)
    Zr(X0R, 49152);
    Zr(X1R, 32768);
    Zr(C0, 32768);  Zr(C1, 32768);
    Zr(d_out, 1);
    Zr(ZALL + (size_t)3232 * 2048, 98304);   // zall pad rows (incl. counter/slot block)

    k_convhs<<<dim3(12800), dim3(256), 0, stream>>>(hs_pad, HS, (unsigned int*)(void*)HS8, 3276800);
    k_conv4<<<dim3(1024),  dim3(256), 0, stream>>>(Wenc, WENC, 262144);
    k_conv8<<<dim3(1024),  dim3(256), 0, stream>>>(Wdec, (unsigned int*)(void*)WDEC8, 262144);
    k_cat2_8<<<dim3(12288), dim3(256), 0, stream>>>(W_ih0, W_hh0, (unsigned int*)(void*)WC08, 4096, 2048, 1024);
    k_cat2_8<<<dim3(8192),  dim3(256), 0, stream>>>(W_ih1, W_hh1, (unsigned int*)(void*)WC18, 4096, 1024, 1024);
    k_woutpad<<<dim3(40960), dim3(256), 0, stream>>>(Wout, WOUTP);
    k_bsum<<<dim3(32), dim3(256), 0, stream>>>(b_ih0, b_hh0, b_ih1, b_hh1, BS0, BS1);
    k_eys8<<<dim3(3232), dim3(256), 0, stream>>>(embed, ys_pad, (unsigned int*)(void*)EYS8);

    // pre_enc = fp8(tanh(hs @ Wenc^T + benc))   (HS dead afterwards -> GP1)
    k_gemm128<<<dim3(8, 100), dim3(256), 0, stream>>>(HS, WENC, 1024, 1024, benc, PRE8, (float*)nullptr, 0);
    k_dq0<<<dim3(128), dim3(256), 0, stream>>>(bdec, DQ);

    // ---- the scan
    SArgs sa;
    sa.pre8 = PRE8; sa.hs8 = HS8; sa.eys8 = EYS8;
    sa.wc0 = WC08;  sa.wc1 = WC18; sa.wdec = WDEC8;
    sa.dq = DQ;     sa.x0r = X0R;  sa.x1r = X1R; sa.zall = ZALL;
    sa.bdec = bdec; sa.bs0 = BS0;  sa.bs1 = BS1;
    sa.c0 = C0;     sa.c1 = C1;    sa.gp = GP;  sa.gp1 = GP1;
    sa.part = PART; sa.lmaxg = LMAX; sa.lsumg = LSUM;
    sa.cntA = CNT;            // 32 counters, stride 32 ints
    sa.cnt0 = CNT + 1024;     // 64 counters, stride 32 ints
    sa.cnt1 = CNT + 3072;     // 64 counters, stride 32 ints
    sa.bslots = CNT + 5120;   // 256 store-report slots
    sa.zslot  = CNT + 5376;   // 64 z0-ready flags
    sa.dqslot = CNT + 5440;   // 64 dq-ready flags
    sa.hlens = hlens;
    void* kp[] = { &sa };
    hipLaunchCooperativeKernel((const void*)k_scan, dim3(256), dim3(256), kp, 0, stream);

    // ---- output projection + CE
    k_gemm128<<<dim3(40, 26), dim3(256), 0, stream>>>(ZALL, WOUTP, 2048, 5120, (const float*)nullptr,
                                                      (unsigned char*)nullptr, Y, 1);
    k_ce<<<dim3(3232), dim3(256), 0, stream>>>(Y, bout, ys_pad, out);
}

// Round 5
// 4628.507 us; speedup vs baseline: 1.2248x; 1.2248x over previous
//
#include <hip/hip_runtime.h>
#include <cstdint>
#include <cstddef>

// ---------------------------------------------------------------------------
// E2E AttDot + 2-layer LSTM decoder + CE loss. B=32,T=400,D=E=1024,V=5000,L=100.
// R8: full-K cell phases (no cross-block K-reduction): 256 blocks x (4 d x 4
// gates x full K), intra-block LDS reduce, c-state in LDS, small published
// activation vectors (attp/z0p/z1p/dqp). R6 tree barrier (3/step) retained.
// ---------------------------------------------------------------------------

using short8  = __attribute__((ext_vector_type(8))) short;
using floatx4 = __attribute__((ext_vector_type(4))) float;
using floatx2 = __attribute__((ext_vector_type(2))) float;
typedef unsigned long long u64;

#define DEV __device__ __forceinline__

#if defined(__has_builtin)
#if __has_builtin(__builtin_amdgcn_cvt_pk_f32_fp8) && __has_builtin(__builtin_amdgcn_cvt_pk_fp8_f32)
#define HW_FP8 1
#endif
#endif

DEV float bf2f(unsigned int h) { union { unsigned int u; float f; } v; v.u = h << 16; return v.f; }
DEV unsigned short f2bf(float f) {
    union { float f; unsigned int u; } v; v.f = f;
    return (unsigned short)((v.u + 0x7fffu + ((v.u >> 16) & 1u)) >> 16);
}
DEV float sigm(float x) { return 1.0f / (1.0f + __expf(-x)); }

// ---- fp8 e4m3 software codecs (fallback + setup use)
DEV float fp8tof_sw(unsigned int b) {
    unsigned int s = (b & 0x80u) << 24;
    unsigned int em = b & 0x7fu;
    float vn = __uint_as_float(s | ((em + 960u) << 20));
    float vd = (float)(int)em * 0x1p-9f;
    vd = s ? -vd : vd;
    return (em >= 8u) ? vn : vd;
}
DEV unsigned int f2fp8_sw(float f) {
    unsigned int u = __float_as_uint(f);
    unsigned int s = (u >> 24) & 0x80u;
    unsigned int a = u & 0x7fffffffu;
    if (a >= 0x43e00000u) return s | 0x7eu;            // clamp +-448
    if (a < 0x3c800000u) {                              // denorm: m = rne(|f|*512)
        unsigned int mi = (unsigned int)(__uint_as_float(a) * 512.0f + 0.5f);
        return s | mi;
    }
    unsigned int lsb = (a >> 20) & 1u;
    a += 0x0007ffffu + lsb;
    unsigned int e = (a >> 23) - 120u;
    unsigned int m = (a >> 20) & 7u;
    return s | (e << 3) | m;
}
DEV void un4(unsigned int w, float* o) {
#ifdef HW_FP8
    floatx2 lo = __builtin_amdgcn_cvt_pk_f32_fp8((int)w, false);
    floatx2 hi = __builtin_amdgcn_cvt_pk_f32_fp8((int)w, true);
    o[0] = lo.x; o[1] = lo.y; o[2] = hi.x; o[3] = hi.y;
#else
    o[0] = fp8tof_sw(w & 0xffu); o[1] = fp8tof_sw((w >> 8) & 0xffu);
    o[2] = fp8tof_sw((w >> 16) & 0xffu); o[3] = fp8tof_sw(w >> 24);
#endif
}
DEV unsigned int pack4fp8(float a, float b, float c, float d) {
#ifdef HW_FP8
    int w = __builtin_amdgcn_cvt_pk_fp8_f32(a, b, 0, false);
    w = __builtin_amdgcn_cvt_pk_fp8_f32(c, d, w, true);
    return (unsigned int)w;
#else
    return f2fp8_sw(a) | (f2fp8_sw(b) << 8) | (f2fp8_sw(c) << 16) | (f2fp8_sw(d) << 24);
#endif
}
DEV unsigned char f2fp8_1(float v) {
#ifdef HW_FP8
    return (unsigned char)((unsigned int)__builtin_amdgcn_cvt_pk_fp8_f32(v, v, 0, false) & 0xffu);
#else
    return (unsigned char)f2fp8_sw(v);
#endif
}
DEV u64 pack4bf16(float a, float b, float c, float d) {
    union { unsigned int w[2]; u64 q; } u;
    u.w[0] = (unsigned int)f2bf(a) | ((unsigned int)f2bf(b) << 16);
    u.w[1] = (unsigned int)f2bf(c) | ((unsigned int)f2bf(d) << 16);
    return u.q;
}

// relaxed agent-scope accessors (per-access coherence, no cache-wide inv)
DEV u64  lda64(const void* p) { return __hip_atomic_load((const u64*)p, __ATOMIC_RELAXED, __HIP_MEMORY_SCOPE_AGENT); }
DEV void sta64(void* p, u64 v) { __hip_atomic_store((u64*)p, v, __ATOMIC_RELAXED, __HIP_MEMORY_SCOPE_AGENT); }
DEV void sta32(void* p, unsigned int v) { __hip_atomic_store((unsigned int*)p, v, __ATOMIC_RELAXED, __HIP_MEMORY_SCOPE_AGENT); }
DEV float ldaf(const void* p) { return __hip_atomic_load((const float*)p, __ATOMIC_RELAXED, __HIP_MEMORY_SCOPE_AGENT); }
DEV void staf(void* p, float v) { __hip_atomic_store((float*)p, v, __ATOMIC_RELAXED, __HIP_MEMORY_SCOPE_AGENT); }
DEV int  arrive(int* p) { return __hip_atomic_fetch_add(p, 1, __ATOMIC_RELAXED, __HIP_MEMORY_SCOPE_AGENT); }

// ---------------------------------------------------------------- utilities
__global__ __launch_bounds__(256) void k_zero(unsigned int* p, int n) {
    int i = blockIdx.x * 256 + threadIdx.x;
    if (i < n) p[i] = 0u;
}

__global__ __launch_bounds__(256) void k_conv4(const float* __restrict__ in,
                                               unsigned short* __restrict__ out, int n4) {
    int i = blockIdx.x * 256 + threadIdx.x;
    if (i >= n4) return;
    float4 v = ((const float4*)in)[i];
    unsigned int w0 = (unsigned int)f2bf(v.x) | ((unsigned int)f2bf(v.y) << 16);
    unsigned int w1 = (unsigned int)f2bf(v.z) | ((unsigned int)f2bf(v.w) << 16);
    ((uint2*)(void*)out)[i] = make_uint2(w0, w1);
}

// hs: f32 -> bf16 (for pre-GEMM) + fp8 (for attention)
__global__ __launch_bounds__(256) void k_convhs(const float* __restrict__ in,
                                                unsigned short* __restrict__ obf,
                                                unsigned int* __restrict__ o8, int n4) {
    int i = blockIdx.x * 256 + threadIdx.x;
    if (i >= n4) return;
    float4 v = ((const float4*)in)[i];
    unsigned int w0 = (unsigned int)f2bf(v.x) | ((unsigned int)f2bf(v.y) << 16);
    unsigned int w1 = (unsigned int)f2bf(v.z) | ((unsigned int)f2bf(v.w) << 16);
    ((uint2*)(void*)obf)[i] = make_uint2(w0, w1);
    o8[i] = pack4fp8(v.x, v.y, v.z, v.w);
}

__global__ __launch_bounds__(256) void k_conv8(const float* __restrict__ in,
                                               unsigned int* __restrict__ o8, int n4) {
    int i = blockIdx.x * 256 + threadIdx.x;
    if (i >= n4) return;
    float4 v = ((const float4*)in)[i];
    o8[i] = pack4fp8(v.x, v.y, v.z, v.w);
}

// permuted fp8 cat: out row for gate-row n = ((n&1023)>>2)*16 + (n>>10)*4 + (n&3)
// (block dc owns rows {g*1024 + dc*4 + j} stored contiguously as [dc][16][K])
__global__ __launch_bounds__(256) void k_catp8(const float* __restrict__ A, const float* __restrict__ Bsrc,
                                               unsigned int* __restrict__ dst, int Ka, int Kb) {
    int idx = blockIdx.x * 256 + threadIdx.x;
    int K4 = (Ka + Kb) >> 2;
    if (idx >= 4096 * K4) return;
    int n = idx / K4, k4 = idx - n * K4, k = k4 * 4;
    const float* src = (k < Ka) ? (A + (size_t)n * Ka + k) : (Bsrc + (size_t)n * Kb + (k - Ka));
    int outrow = ((n & 1023) >> 2) * 16 + (n >> 10) * 4 + (n & 3);
    dst[(size_t)outrow * K4 + k4] = pack4fp8(src[0], src[1], src[2], src[3]);
}

__global__ __launch_bounds__(256) void k_woutpad(const float* __restrict__ W, unsigned short* __restrict__ dst) {
    int idx = blockIdx.x * 256 + threadIdx.x;
    if (idx >= 5120 * 2048) return;
    int n = idx >> 11, k = idx & 2047;
    dst[idx] = (n < 5000) ? f2bf(W[(size_t)n * 2048 + k]) : (unsigned short)0;
}

__global__ __launch_bounds__(256) void k_bsum(const float* a0, const float* b0, const float* a1, const float* b1,
                                              float* s0, float* s1) {
    int i = blockIdx.x * 256 + threadIdx.x;
    if (i < 4096) s0[i] = a0[i] + b0[i];
    else if (i < 8192) s1[i - 4096] = a1[i - 4096] + b1[i - 4096];
}

// eys fp8 [l][b][1024]
__global__ __launch_bounds__(256) void k_eys8(const float* __restrict__ embed, const int* __restrict__ ys_pad,
                                              unsigned int* __restrict__ eys8) {
    int idx = blockIdx.x * 256 + threadIdx.x;
    if (idx >= 3232 * 256) return;
    int rb = idx >> 8, c4 = idx & 255;
    int l = rb >> 5, b = rb & 31;
    int tok = (l == 0) ? 4999 : ys_pad[b * 100 + (l - 1)];
    const float* e = embed + (size_t)tok * 1024 + c4 * 4;
    eys8[idx] = pack4fp8(e[0], e[1], e[2], e[3]);
}

// dq init: z0=0 -> dq = tanh(bdec)
__global__ __launch_bounds__(256) void k_dq0(const float* __restrict__ bdec, unsigned short* __restrict__ dq) {
    int idx = blockIdx.x * 256 + threadIdx.x;
    if (idx >= 32768) return;
    dq[idx] = f2bf(tanhf(bdec[idx & 1023]));
}

// --------------------------------------------------- big 128x128 MFMA GEMM
// mode0: o8 = fp8(tanh(C+bias));  mode1: of32 = C
__global__ __launch_bounds__(256) void k_gemm128(
    const unsigned short* __restrict__ A, const unsigned short* __restrict__ B,
    int K, int N, const float* __restrict__ bias,
    unsigned char* __restrict__ o8, float* __restrict__ of32, int mode) {
    __shared__ uint4 Ab[512];
    __shared__ uint4 Bb[512];
    const int tid = threadIdx.x;
    const int lane = tid & 63, wave = tid >> 6;
    const int r = lane & 15, q = lane >> 4;
    const int wm = wave >> 1, wn = wave & 1;
    const size_t am0 = (size_t)blockIdx.y * 128;
    const size_t bn0 = (size_t)blockIdx.x * 128;
    floatx4 zf = {0.f, 0.f, 0.f, 0.f};
    floatx4 acc[4][4];
#pragma unroll
    for (int i = 0; i < 4; i++)
#pragma unroll
        for (int j = 0; j < 4; j++) acc[i][j] = zf;

    for (int k0 = 0; k0 < K; k0 += 32) {
        __syncthreads();
#pragma unroll
        for (int i = 0; i < 2; ++i) {
            int idx = i * 256 + tid;
            int qq = idx & 3, rr = idx >> 2;
            int slot = (rr >> 4) * 64 + ((qq << 4) | (rr & 15));
            Ab[slot] = *(const uint4*)(const void*)(A + (am0 + rr) * K + k0 + qq * 8);
            Bb[slot] = *(const uint4*)(const void*)(B + (bn0 + rr) * K + k0 + qq * 8);
        }
        __syncthreads();
        short8 af[4], bf[4];
#pragma unroll
        for (int t = 0; t < 4; t++) af[t] = *(const short8*)(const void*)&Ab[(wm * 4 + t) * 64 + lane];
#pragma unroll
        for (int t = 0; t < 4; t++) bf[t] = *(const short8*)(const void*)&Bb[(wn * 4 + t) * 64 + lane];
#pragma unroll
        for (int tm = 0; tm < 4; tm++)
#pragma unroll
            for (int tn = 0; tn < 4; tn++)
                acc[tm][tn] = __builtin_amdgcn_mfma_f32_16x16x32_bf16(af[tm], bf[tn], acc[tm][tn], 0, 0, 0);
    }
#pragma unroll
    for (int tm = 0; tm < 4; tm++) {
#pragma unroll
        for (int tn = 0; tn < 4; tn++) {
            int col = (int)bn0 + wn * 64 + tn * 16 + r;
#pragma unroll
            for (int reg = 0; reg < 4; ++reg) {
                size_t row = am0 + wm * 64 + tm * 16 + q * 4 + reg;
                float v = acc[tm][tn][reg];
                if (mode == 0) {
                    v = tanhf(v + bias[col]);
                    o8[row * (size_t)N + col] = f2fp8_1(v);
                } else {
                    of32[row * (size_t)N + col] = v;
                }
            }
        }
    }
}

// ------------------------------------------------- persistent scan kernel
struct SArgs {
    const unsigned char* pre8;   // [12800][1024] fp8
    const unsigned char* hs8;    // [12800][1024] fp8
    const unsigned char* eys8;   // [3232][1024] fp8
    const unsigned char* wc0p;   // [256*16][3072] fp8 (permuted rows)
    const unsigned char* wc1p;   // [256*16][2048] fp8 (permuted rows)
    const unsigned char* wdec;   // [1024][1024] fp8 (identity layout)
    unsigned short* dq;          // [32][1024] bf16
    unsigned char* attp;         // [32][1024] fp8
    unsigned char* z0p;          // [2][32][1024] fp8 (double-buffered)
    unsigned char* z1p;          // [2][32][1024] fp8 (double-buffered)
    unsigned short* zall;        // [3328][2048] bf16
    const float* bdec; const float* bs0; const float* bs1;
    float* part; float* lmaxg; float* lsumg;
    int* cntA; int* gcnt; int* gflag;
    const int* hlens;
};

// two-level tree barrier (R6-proven): 8 groups x 32 arrivals on separate
// 128B lines; group-last arrives at master; master-last publishes gflag.
DEV void gbar(int* gcnt, int* gflag, int ep, int grp) {
    __builtin_amdgcn_s_waitcnt(0);
    __syncthreads();
    if (threadIdx.x == 0) {
        int old = arrive(gcnt + grp * 32);
        if (old == ep * 32 - 1) {
            int o2 = arrive(gcnt + 256);
            if (o2 == ep * 8 - 1) {
                __hip_atomic_store(gflag, ep, __ATOMIC_RELAXED, __HIP_MEMORY_SCOPE_AGENT);
            }
        }
        while (__hip_atomic_load(gflag, __ATOMIC_RELAXED, __HIP_MEMORY_SCOPE_AGENT) < ep)
            __builtin_amdgcn_s_sleep(1);
    }
    __syncthreads();
}

__global__ __launch_bounds__(256, 1) void k_scan(SArgs a) {
    const int blk = blockIdx.x, tid = threadIdx.x;
    const int lane = tid & 63, wave = tid >> 6;
    const int b = blk >> 3, ch = blk & 7;       // attention role
    const int dc = blk;                          // cell role: d = dc*4..+3, 4 gates
    const int grp = blk & 7;
    const int r = lane & 15, q = lane >> 4;
    const int hlen = a.hlens[b];

    __shared__ __align__(16) unsigned char hsS[51200];   // 50x1024 fp8 (whole slice)
    __shared__ __align__(16) unsigned char xS[32 * 3088]; // staging: B 32x3072(+16 pad); C 32x2048(+16); A dq 2KB
    __shared__ __align__(16) float redS[4][64][8];       // per-wave MFMA partials
    __shared__ float e4[50][4];
    __shared__ float es[52];
    __shared__ float ps[52];
    __shared__ float c0S[4][32], c1S[4][32];             // block-private cell state
    __shared__ unsigned char  z8tmp[128];
    __shared__ unsigned short z16tmp[128];
    __shared__ unsigned short dq16tmp[128];
    __shared__ int lastf;

    // one-time: hs slice -> LDS (plain loads; setup-written), c-state zero
    {
        const u64* hsrc = (const u64*)(const void*)(a.hs8 + (size_t)(b * 400 + ch * 50) * 1024);
        u64* hd = (u64*)(void*)hsS;
        for (int i = tid; i < 6400; i += 256) hd[i] = hsrc[i];
        if (tid < 128) { c0S[tid >> 5][tid & 31] = 0.f; c1S[tid >> 5][tid & 31] = 0.f; }
    }
    __syncthreads();

    int ep = 0;
    for (int l = 0; l < 101; ++l) {
        unsigned char* z0cur = a.z0p + (size_t)(l & 1) * 32768;
        unsigned char* z0prv = a.z0p + (size_t)((l + 1) & 1) * 32768;
        unsigned char* z1cur = a.z1p + (size_t)(l & 1) * 32768;
        unsigned char* z1prv = a.z1p + (size_t)((l + 1) & 1) * 32768;

        // ================= phase A: attention =================
        {
            // stage dq[b] (2 KB bf16) into xS head
            ((u64*)(void*)xS)[tid] = lda64((const char*)(const void*)a.dq + (size_t)b * 2048 + tid * 8);
            __syncthreads();
            float dqf[16];
            {
                const unsigned int* dw = (const unsigned int*)(const void*)xS + lane * 8;
#pragma unroll
                for (int i = 0; i < 8; ++i) {
                    unsigned int w = dw[i];
                    dqf[2 * i] = bf2f(w & 0xffffu);
                    dqf[2 * i + 1] = bf2f(w >> 16);
                }
            }
            // e partials: pre8 from GLOBAL (L2-resident; plain loads)
            const uint4* prow = (const uint4*)(const void*)(a.pre8 + (size_t)(b * 400 + ch * 50) * 1024);
            for (int tl = wave; tl < 50; tl += 4) {
                uint4 v = prow[tl * 64 + lane];
                float x[16];
                un4(v.x, x); un4(v.y, x + 4); un4(v.z, x + 8); un4(v.w, x + 12);
                float s = 0.f;
#pragma unroll
                for (int i = 0; i < 16; ++i) s += x[i] * dqf[i];
                s += __shfl_xor(s, 1, 64);
                s += __shfl_xor(s, 2, 64);
                s += __shfl_xor(s, 4, 64);
                s += __shfl_xor(s, 8, 64);
                if ((lane & 15) == 0) e4[tl][lane >> 4] = s;
            }
            __syncthreads();
            if (tid < 50) {
                float4 v = *(const float4*)(const void*)e4[tid];
                float e = v.x + v.y + v.z + v.w;
                int t = ch * 50 + tid;
                es[tid] = (t < hlen) ? 2.0f * e : -1e30f;
            }
            __syncthreads();
            float lmax = -1e30f;
#pragma unroll
            for (int i = 0; i < 50; ++i) lmax = fmaxf(lmax, es[i]);
            if (tid < 50) ps[tid] = (es[tid] > -5e29f) ? __expf(es[tid] - lmax) : 0.f;
            __syncthreads();
            if (tid == 0) {
                float ssum = 0.f;
                for (int i = 0; i < 50; ++i) ssum += ps[i];
                staf(a.lmaxg + b * 8 + ch, lmax);
                staf(a.lsumg + b * 8 + ch, ssum);
            }
            const int c = tid * 4;
            float a0 = 0.f, a1 = 0.f, a2 = 0.f, a3 = 0.f;
            for (int tl = 0; tl < 50; ++tl) {
                float p = ps[tl];
                unsigned int h = *(const unsigned int*)(const void*)(hsS + tl * 1024 + c);
                float x[4];
                un4(h, x);
                a0 += p * x[0]; a1 += p * x[1]; a2 += p * x[2]; a3 += p * x[3];
            }
            {
                float* pb = a.part + ((size_t)(b * 8 + ch)) * 1024 + c;
                union { float f[2]; u64 q; } p0, p1;
                p0.f[0] = a0; p0.f[1] = a1; p1.f[0] = a2; p1.f[1] = a3;
                sta64(pb, p0.q); sta64(pb + 2, p1.q);
            }
            __builtin_amdgcn_s_waitcnt(0);
            __syncthreads();
            if (tid == 0) lastf = (arrive(a.cntA + b * 32) == 8 * l + 7);
            __syncthreads();
            if (lastf) {
                float lm[8], ls[8];
#pragma unroll
                for (int i = 0; i < 8; ++i) {
                    lm[i] = ldaf(a.lmaxg + b * 8 + i);
                    ls[i] = ldaf(a.lsumg + b * 8 + i);
                }
                float gm = -1e30f;
#pragma unroll
                for (int i = 0; i < 8; ++i) gm = fmaxf(gm, lm[i]);
                float Zs = 0.f;
#pragma unroll
                for (int i = 0; i < 8; ++i) Zs += ls[i] * __expf(lm[i] - gm);
                const float inv = 1.0f / Zs;
                float o0 = 0.f, o1 = 0.f, o2 = 0.f, o3 = 0.f;
#pragma unroll
                for (int i = 0; i < 8; ++i) {
                    float coef = __expf(lm[i] - gm) * inv;
                    const float* qp = a.part + ((size_t)(b * 8 + i)) * 1024 + c;
                    union { u64 q; float f[2]; } u0, u1;
                    u0.q = lda64(qp); u1.q = lda64(qp + 2);
                    o0 += coef * u0.f[0]; o1 += coef * u0.f[1];
                    o2 += coef * u1.f[0]; o3 += coef * u1.f[1];
                }
                sta32(a.attp + (size_t)b * 1024 + c, pack4fp8(o0, o1, o2, o3));
                sta64(a.zall + ((size_t)(l * 32 + b)) * 2048 + 1024 + c, pack4bf16(o0, o1, o2, o3));
            }
        }
        gbar(a.gcnt, a.gflag, ++ep, grp);

        // ================= phase B: LSTM cell 0 (full K=3072) =================
        {
            // stage xS[b][3072] = [ey | att | z0prev], row stride 3088
            {
                const uint4* ey = (const uint4*)(const void*)(a.eys8 + (size_t)l * 32768);
                for (int i = tid; i < 2048; i += 256) {
                    int row = i >> 6, off = i & 63;
                    *(uint4*)(void*)&xS[row * 3088 + off * 16] = ey[row * 64 + off];
                }
                for (int i = tid; i < 4096; i += 256) {
                    int row = i >> 7, off = i & 127;
                    *(u64*)(void*)&xS[row * 3088 + 1024 + off * 8] = lda64(a.attp + (size_t)row * 1024 + off * 8);
                }
                for (int i = tid; i < 4096; i += 256) {
                    int row = i >> 7, off = i & 127;
                    *(u64*)(void*)&xS[row * 3088 + 2048 + off * 8] = lda64(z0prv + (size_t)row * 1024 + off * 8);
                }
            }
            __syncthreads();
            const unsigned char* Br = a.wc0p + ((size_t)(dc * 16 + r)) * 3072 + wave * 768 + q * 8;
            const unsigned char* A0 = &xS[r * 3088 + wave * 768 + q * 8];
            const unsigned char* A1 = A0 + 16 * 3088;
            floatx4 acc0 = {0.f, 0.f, 0.f, 0.f}, acc1 = acc0;
#pragma unroll 8
            for (int kk = 0; kk < 768; kk += 32) {
                long long bfr = *(const long long*)(const void*)(Br + kk);
                long long a0 = *(const long long*)(const void*)(A0 + kk);
                long long a1 = *(const long long*)(const void*)(A1 + kk);
                acc0 = __builtin_amdgcn_mfma_f32_16x16x32_fp8_fp8(a0, bfr, acc0, 0, 0, 0);
                acc1 = __builtin_amdgcn_mfma_f32_16x16x32_fp8_fp8(a1, bfr, acc1, 0, 0, 0);
            }
            *(floatx4*)(void*)&redS[wave][lane][0] = acc0;
            *(floatx4*)(void*)&redS[wave][lane][4] = acc1;
            __syncthreads();
            if (tid < 128) {
                const int bb = tid & 31, j = tid >> 5;
                const int qp = (bb & 15) >> 2;
                const int slot = (bb & 3) + ((bb >> 4) << 2);
                float g[4];
#pragma unroll
                for (int gg = 0; gg < 4; ++gg) {
                    const int lp = (qp << 4) | (gg * 4 + j);
                    g[gg] = redS[0][lp][slot] + redS[1][lp][slot] + redS[2][lp][slot] + redS[3][lp][slot]
                          + a.bs0[gg * 1024 + dc * 4 + j];
                }
                float cn = sigm(g[1]) * c0S[j][bb] + sigm(g[0]) * tanhf(g[2]);
                c0S[j][bb] = cn;
                float z = sigm(g[3]) * tanhf(cn);
                z8tmp[bb * 4 + j] = f2fp8_1(z);
            }
            __syncthreads();
            if (tid < 32) {
                unsigned int w = *(const unsigned int*)(const void*)&z8tmp[tid * 4];
                sta32(z0cur + (size_t)tid * 1024 + dc * 4, w);
            }
        }
        gbar(a.gcnt, a.gflag, ++ep, grp);

        // ================= phase C: LSTM cell 1 (full K=2048) + dq =================
        {
            // stage xS[b][2048] = [z0 | z1prev], row stride 2064
            for (int i = tid; i < 4096; i += 256) {
                int row = i >> 7, off = i & 127;
                *(u64*)(void*)&xS[row * 2064 + off * 8] = lda64(z0cur + (size_t)row * 1024 + off * 8);
            }
            for (int i = tid; i < 4096; i += 256) {
                int row = i >> 7, off = i & 127;
                *(u64*)(void*)&xS[row * 2064 + 1024 + off * 8] = lda64(z1prv + (size_t)row * 1024 + off * 8);
            }
            __syncthreads();
            // gates (K=2048, wave window 512)
            {
                const unsigned char* Br = a.wc1p + ((size_t)(dc * 16 + r)) * 2048 + wave * 512 + q * 8;
                const unsigned char* A0 = &xS[r * 2064 + wave * 512 + q * 8];
                const unsigned char* A1 = A0 + 16 * 2064;
                floatx4 acc0 = {0.f, 0.f, 0.f, 0.f}, acc1 = acc0;
#pragma unroll 8
                for (int kk = 0; kk < 512; kk += 32) {
                    long long bfr = *(const long long*)(const void*)(Br + kk);
                    long long a0 = *(const long long*)(const void*)(A0 + kk);
                    long long a1 = *(const long long*)(const void*)(A1 + kk);
                    acc0 = __builtin_amdgcn_mfma_f32_16x16x32_fp8_fp8(a0, bfr, acc0, 0, 0, 0);
                    acc1 = __builtin_amdgcn_mfma_f32_16x16x32_fp8_fp8(a1, bfr, acc1, 0, 0, 0);
                }
                *(floatx4*)(void*)&redS[wave][lane][0] = acc0;
                *(floatx4*)(void*)&redS[wave][lane][4] = acc1;
            }
            __syncthreads();
            if (tid < 128) {
                const int bb = tid & 31, j = tid >> 5;
                const int qp = (bb & 15) >> 2;
                const int slot = (bb & 3) + ((bb >> 4) << 2);
                float g[4];
#pragma unroll
                for (int gg = 0; gg < 4; ++gg) {
                    const int lp = (qp << 4) | (gg * 4 + j);
                    g[gg] = redS[0][lp][slot] + redS[1][lp][slot] + redS[2][lp][slot] + redS[3][lp][slot]
                          + a.bs1[gg * 1024 + dc * 4 + j];
                }
                float cn = sigm(g[1]) * c1S[j][bb] + sigm(g[0]) * tanhf(g[2]);
                c1S[j][bb] = cn;
                float z = sigm(g[3]) * tanhf(cn);
                z8tmp[bb * 4 + j] = f2fp8_1(z);
                z16tmp[bb * 4 + j] = f2bf(z);
            }
            __syncthreads();   // redS reuse guard
            // dq = tanh(Wdec z0 + bdec), rows dc*4..+3 (K=1024, wave window 256)
            {
                const unsigned char* Bd = a.wdec + ((size_t)(dc * 4 + (r & 3))) * 1024 + wave * 256 + q * 8;
                const unsigned char* D0 = &xS[r * 2064 + wave * 256 + q * 8];   // z0 cols
                const unsigned char* D1 = D0 + 16 * 2064;
                floatx4 acc0 = {0.f, 0.f, 0.f, 0.f}, acc1 = acc0;
#pragma unroll 8
                for (int kk = 0; kk < 256; kk += 32) {
                    long long bfr = *(const long long*)(const void*)(Bd + kk);
                    long long a0 = *(const long long*)(const void*)(D0 + kk);
                    long long a1 = *(const long long*)(const void*)(D1 + kk);
                    acc0 = __builtin_amdgcn_mfma_f32_16x16x32_fp8_fp8(a0, bfr, acc0, 0, 0, 0);
                    acc1 = __builtin_amdgcn_mfma_f32_16x16x32_fp8_fp8(a1, bfr, acc1, 0, 0, 0);
                }
                *(floatx4*)(void*)&redS[wave][lane][0] = acc0;
                *(floatx4*)(void*)&redS[wave][lane][4] = acc1;
            }
            __syncthreads();
            if (tid < 128) {
                const int bb = tid & 31, j = tid >> 5;
                const int qp = (bb & 15) >> 2;
                const int slot = (bb & 3) + ((bb >> 4) << 2);
                const int lp = (qp << 4) | j;   // cols 4..15 are duplicates
                float s = redS[0][lp][slot] + redS[1][lp][slot] + redS[2][lp][slot] + redS[3][lp][slot];
                dq16tmp[bb * 4 + j] = f2bf(tanhf(s + a.bdec[dc * 4 + j]));
            }
            __syncthreads();
            if (tid < 32) {
                unsigned int wz = *(const unsigned int*)(const void*)&z8tmp[tid * 4];
                sta32(z1cur + (size_t)tid * 1024 + dc * 4, wz);
                u64 wq = *(const u64*)(const void*)&z16tmp[tid * 4];
                sta64(a.zall + ((size_t)(l * 32 + tid)) * 2048 + dc * 4, wq);
                u64 wd = *(const u64*)(const void*)&dq16tmp[tid * 4];
                sta64((char*)(void*)a.dq + (size_t)tid * 2048 + dc * 8, wd);
            }
        }
        gbar(a.gcnt, a.gflag, ++ep, grp);
    }
}

// ----------------------------------------------------------- CE reduction
__global__ __launch_bounds__(256) void k_ce(const float* __restrict__ y, const float* __restrict__ bout,
                                            const int* __restrict__ ys_pad, float* __restrict__ out) {
    const int rrow = blockIdx.x;
    const int l = rrow >> 5, b = rrow & 31;
    const float* yp = y + (size_t)rrow * 5120;
    const int tid = threadIdx.x;
    __shared__ float red[256];
    float m = -1e30f;
    for (int c = tid; c < 5000; c += 256) m = fmaxf(m, yp[c] + bout[c]);
    red[tid] = m; __syncthreads();
    for (int s = 128; s; s >>= 1) { if (tid < s) red[tid] = fmaxf(red[tid], red[tid + s]); __syncthreads(); }
    const float gmax = red[0]; __syncthreads();
    float ss = 0.f;
    for (int c = tid; c < 5000; c += 256) ss += __expf(yp[c] + bout[c] - gmax);
    red[tid] = ss; __syncthreads();
    for (int s = 128; s; s >>= 1) { if (tid < s) red[tid] += red[tid + s]; __syncthreads(); }
    if (tid == 0) {
        const int tgt = (l < 100) ? ys_pad[b * 100 + l] : 4999;
        const float lt = yp[tgt] + bout[tgt];
        const float ce = logf(red[0]) + gmax - lt;
        atomicAdd(out, ce * (100.0f / 3232.0f));
    }
}

// ---------------------------------------------------------------------------
extern "C" void kernel_launch(void* const* d_in, const int* in_sizes, int n_in,
                              void* d_out, int out_size, void* d_ws, size_t ws_size,
                              hipStream_t stream) {
    const float* hs_pad = (const float*)d_in[0];
    const float* embed  = (const float*)d_in[1];
    const float* Wenc   = (const float*)d_in[2];
    const float* benc   = (const float*)d_in[3];
    const float* Wdec   = (const float*)d_in[4];
    const float* bdec   = (const float*)d_in[5];
    const float* W_ih0  = (const float*)d_in[6];
    const float* W_hh0  = (const float*)d_in[7];
    const float* b_ih0  = (const float*)d_in[8];
    const float* b_hh0  = (const float*)d_in[9];
    const float* W_ih1  = (const float*)d_in[10];
    const float* W_hh1  = (const float*)d_in[11];
    const float* b_ih1  = (const float*)d_in[12];
    const float* b_hh1  = (const float*)d_in[13];
    const float* Wout   = (const float*)d_in[14];
    const float* bout   = (const float*)d_in[15];
    const int*   hlens  = (const int*)d_in[16];
    const int*   ys_pad = (const int*)d_in[17];
    float* out = (float*)d_out;
    uint8_t* ws = (uint8_t*)d_ws;

    // layout: dead-by-final-GEMM buffers first (Y f32 68.2MB aliases them)
    constexpr size_t OFF_HS    = 0;                        // 26,214,400 bf16 hs (dead after pre-GEMM)
    constexpr size_t OFF_PRE8  = OFF_HS    + 26214400;     // 13,107,200
    constexpr size_t OFF_HS8   = OFF_PRE8  + 13107200;     // 13,107,200
    constexpr size_t OFF_WC0P  = OFF_HS8   + 13107200;     // 12,582,912
    constexpr size_t OFF_WC1P  = OFF_WC0P  + 12582912;     //  8,388,608
    constexpr size_t OFF_WDEC8 = OFF_WC1P  + 8388608;      //  1,048,576
    constexpr size_t OFF_WENC  = OFF_WDEC8 + 1048576;      //  2,097,152 bf16
    constexpr size_t OFF_EYS8  = OFF_WENC  + 2097152;      //  3,309,568
    constexpr size_t OFF_ZALL  = OFF_EYS8  + 3309568;      // 13,631,488 bf16 (survives final GEMM)
    constexpr size_t OFF_WOUT  = OFF_ZALL  + 13631488;     // 20,971,520 bf16 (survives)
    constexpr size_t OFF_PART  = OFF_WOUT  + 20971520;     //  1,048,576
    constexpr size_t OFF_DQP   = OFF_PART  + 1048576;      //  65,536 bf16
    constexpr size_t OFF_ATTP  = OFF_DQP   + 65536;        //  32,768
    constexpr size_t OFF_Z0P   = OFF_ATTP  + 32768;        //  65,536 (x2 buffers)
    constexpr size_t OFF_Z1P   = OFF_Z0P   + 65536;        //  65,536
    constexpr size_t OFF_LMAX  = OFF_Z1P   + 65536;        //  1,024
    constexpr size_t OFF_LSUM  = OFF_LMAX  + 1024;         //  1,024
    constexpr size_t OFF_BS0   = OFF_LSUM  + 1024;         //  16,384
    constexpr size_t OFF_BS1   = OFF_BS0   + 16384;        //  16,384
    constexpr size_t OFF_CNT   = OFF_BS1   + 16384;        //  8,192
    constexpr size_t OFF_Y     = 0;

    unsigned short* HS    = (unsigned short*)(ws + OFF_HS);
    unsigned char*  PRE8  = (unsigned char*)(ws + OFF_PRE8);
    unsigned char*  HS8   = (unsigned char*)(ws + OFF_HS8);
    unsigned char*  WC0P  = (unsigned char*)(ws + OFF_WC0P);
    unsigned char*  WC1P  = (unsigned char*)(ws + OFF_WC1P);
    unsigned char*  WDEC8 = (unsigned char*)(ws + OFF_WDEC8);
    unsigned short* WENC  = (unsigned short*)(ws + OFF_WENC);
    unsigned char*  EYS8  = (unsigned char*)(ws + OFF_EYS8);
    unsigned short* ZALL  = (unsigned short*)(ws + OFF_ZALL);
    unsigned short* WOUTP = (unsigned short*)(ws + OFF_WOUT);
    float* PART  = (float*)(ws + OFF_PART);
    unsigned short* DQP = (unsigned short*)(ws + OFF_DQP);
    unsigned char*  ATTP = (unsigned char*)(ws + OFF_ATTP);
    unsigned char*  Z0P = (unsigned char*)(ws + OFF_Z0P);
    unsigned char*  Z1P = (unsigned char*)(ws + OFF_Z1P);
    float* LMAX  = (float*)(ws + OFF_LMAX);
    float* LSUM  = (float*)(ws + OFF_LSUM);
    float* BS0  = (float*)(ws + OFF_BS0);
    float* BS1  = (float*)(ws + OFF_BS1);
    int* CNT    = (int*)(ws + OFF_CNT);
    float* Y = (float*)(ws + OFF_Y);

    auto Zr = [&](void* p, int n_u32) {
        k_zero<<<dim3((n_u32 + 255) / 256), dim3(256), 0, stream>>>((unsigned int*)p, n_u32);
    };

    // ---- setup (re-done every call)
    Zr(Z0P, 16384);
    Zr(Z1P, 16384);
    Zr(CNT, 2048);
    Zr(d_out, 1);
    Zr(ZALL + (size_t)3232 * 2048, 98304);   // zall pad rows

    k_convhs<<<dim3(12800), dim3(256), 0, stream>>>(hs_pad, HS, (unsigned int*)(void*)HS8, 3276800);
    k_conv4<<<dim3(1024),  dim3(256), 0, stream>>>(Wenc, WENC, 262144);
    k_conv8<<<dim3(1024),  dim3(256), 0, stream>>>(Wdec, (unsigned int*)(void*)WDEC8, 262144);
    k_catp8<<<dim3(12288), dim3(256), 0, stream>>>(W_ih0, W_hh0, (unsigned int*)(void*)WC0P, 2048, 1024);
    k_catp8<<<dim3(8192),  dim3(256), 0, stream>>>(W_ih1, W_hh1, (unsigned int*)(void*)WC1P, 1024, 1024);
    k_woutpad<<<dim3(40960), dim3(256), 0, stream>>>(Wout, WOUTP);
    k_bsum<<<dim3(32), dim3(256), 0, stream>>>(b_ih0, b_hh0, b_ih1, b_hh1, BS0, BS1);
    k_eys8<<<dim3(3232), dim3(256), 0, stream>>>(embed, ys_pad, (unsigned int*)(void*)EYS8);

    // pre_enc = fp8(tanh(hs @ Wenc^T + benc))
    k_gemm128<<<dim3(8, 100), dim3(256), 0, stream>>>(HS, WENC, 1024, 1024, benc, PRE8, (float*)nullptr, 0);
    k_dq0<<<dim3(128), dim3(256), 0, stream>>>(bdec, DQP);

    // ---- the scan
    SArgs sa;
    sa.pre8 = PRE8; sa.hs8 = HS8; sa.eys8 = EYS8;
    sa.wc0p = WC0P; sa.wc1p = WC1P; sa.wdec = WDEC8;
    sa.dq = DQP; sa.attp = ATTP; sa.z0p = Z0P; sa.z1p = Z1P; sa.zall = ZALL;
    sa.bdec = bdec; sa.bs0 = BS0;  sa.bs1 = BS1;
    sa.part = PART; sa.lmaxg = LMAX; sa.lsumg = LSUM;
    sa.cntA = CNT;            // 32 counters, stride 32 ints
    sa.gcnt = CNT + 1024;     // 8 group counters (stride 32) + master at +256
    sa.gflag = CNT + 1536;    // isolated poll line
    sa.hlens = hlens;
    void* kp[] = { &sa };
    hipLaunchCooperativeKernel((const void*)k_scan, dim3(256), dim3(256), kp, 0, stream);

    // ---- output projection + CE
    k_gemm128<<<dim3(40, 26), dim3(256), 0, stream>>>(ZALL, WOUTP, 2048, 5120, (const float*)nullptr,
                                                      (unsigned char*)nullptr, Y, 1);
    k_ce<<<dim3(3232), dim3(256), 0, stream>>>(Y, bout, ys_pad, out);
}

// Round 6
// 3847.178 us; speedup vs baseline: 1.4735x; 1.2031x over previous
//
#include <hip/hip_runtime.h>
#include <cstdint>
#include <cstddef>

// ---------------------------------------------------------------------------
// E2E AttDot + 2-layer LSTM decoder + CE loss. B=32,T=400,D=E=1024,V=5000,L=100.
// R9: pre8+hs8 both LDS-resident (no per-step HBM stream); MFMA A-operands
// read DIRECTLY from global (eys plain / attp,z0,z1 agent) - no xS staging,
// no staging syncs, no LDS bank conflicts on operands. R8 phase structure +
// R6 tree barrier retained.
// ---------------------------------------------------------------------------

using short8  = __attribute__((ext_vector_type(8))) short;
using floatx4 = __attribute__((ext_vector_type(4))) float;
using floatx2 = __attribute__((ext_vector_type(2))) float;
typedef unsigned long long u64;

#define DEV __device__ __forceinline__

#if defined(__has_builtin)
#if __has_builtin(__builtin_amdgcn_cvt_pk_f32_fp8) && __has_builtin(__builtin_amdgcn_cvt_pk_fp8_f32)
#define HW_FP8 1
#endif
#endif

DEV float bf2f(unsigned int h) { union { unsigned int u; float f; } v; v.u = h << 16; return v.f; }
DEV unsigned short f2bf(float f) {
    union { float f; unsigned int u; } v; v.f = f;
    return (unsigned short)((v.u + 0x7fffu + ((v.u >> 16) & 1u)) >> 16);
}
DEV float sigm(float x) { return 1.0f / (1.0f + __expf(-x)); }

// ---- fp8 e4m3 software codecs (fallback + setup use)
DEV float fp8tof_sw(unsigned int b) {
    unsigned int s = (b & 0x80u) << 24;
    unsigned int em = b & 0x7fu;
    float vn = __uint_as_float(s | ((em + 960u) << 20));
    float vd = (float)(int)em * 0x1p-9f;
    vd = s ? -vd : vd;
    return (em >= 8u) ? vn : vd;
}
DEV unsigned int f2fp8_sw(float f) {
    unsigned int u = __float_as_uint(f);
    unsigned int s = (u >> 24) & 0x80u;
    unsigned int a = u & 0x7fffffffu;
    if (a >= 0x43e00000u) return s | 0x7eu;            // clamp +-448
    if (a < 0x3c800000u) {                              // denorm: m = rne(|f|*512)
        unsigned int mi = (unsigned int)(__uint_as_float(a) * 512.0f + 0.5f);
        return s | mi;
    }
    unsigned int lsb = (a >> 20) & 1u;
    a += 0x0007ffffu + lsb;
    unsigned int e = (a >> 23) - 120u;
    unsigned int m = (a >> 20) & 7u;
    return s | (e << 3) | m;
}
DEV void un4(unsigned int w, float* o) {
#ifdef HW_FP8
    floatx2 lo = __builtin_amdgcn_cvt_pk_f32_fp8((int)w, false);
    floatx2 hi = __builtin_amdgcn_cvt_pk_f32_fp8((int)w, true);
    o[0] = lo.x; o[1] = lo.y; o[2] = hi.x; o[3] = hi.y;
#else
    o[0] = fp8tof_sw(w & 0xffu); o[1] = fp8tof_sw((w >> 8) & 0xffu);
    o[2] = fp8tof_sw((w >> 16) & 0xffu); o[3] = fp8tof_sw(w >> 24);
#endif
}
DEV unsigned int pack4fp8(float a, float b, float c, float d) {
#ifdef HW_FP8
    int w = __builtin_amdgcn_cvt_pk_fp8_f32(a, b, 0, false);
    w = __builtin_amdgcn_cvt_pk_fp8_f32(c, d, w, true);
    return (unsigned int)w;
#else
    return f2fp8_sw(a) | (f2fp8_sw(b) << 8) | (f2fp8_sw(c) << 16) | (f2fp8_sw(d) << 24);
#endif
}
DEV unsigned char f2fp8_1(float v) {
#ifdef HW_FP8
    return (unsigned char)((unsigned int)__builtin_amdgcn_cvt_pk_fp8_f32(v, v, 0, false) & 0xffu);
#else
    return (unsigned char)f2fp8_sw(v);
#endif
}
DEV u64 pack4bf16(float a, float b, float c, float d) {
    union { unsigned int w[2]; u64 q; } u;
    u.w[0] = (unsigned int)f2bf(a) | ((unsigned int)f2bf(b) << 16);
    u.w[1] = (unsigned int)f2bf(c) | ((unsigned int)f2bf(d) << 16);
    return u.q;
}

// relaxed agent-scope accessors (per-access coherence, no cache-wide inv)
DEV u64  lda64(const void* p) { return __hip_atomic_load((const u64*)p, __ATOMIC_RELAXED, __HIP_MEMORY_SCOPE_AGENT); }
DEV void sta64(void* p, u64 v) { __hip_atomic_store((u64*)p, v, __ATOMIC_RELAXED, __HIP_MEMORY_SCOPE_AGENT); }
DEV void sta32(void* p, unsigned int v) { __hip_atomic_store((unsigned int*)p, v, __ATOMIC_RELAXED, __HIP_MEMORY_SCOPE_AGENT); }
DEV float ldaf(const void* p) { return __hip_atomic_load((const float*)p, __ATOMIC_RELAXED, __HIP_MEMORY_SCOPE_AGENT); }
DEV void staf(void* p, float v) { __hip_atomic_store((float*)p, v, __ATOMIC_RELAXED, __HIP_MEMORY_SCOPE_AGENT); }
DEV int  arrive(int* p) { return __hip_atomic_fetch_add(p, 1, __ATOMIC_RELAXED, __HIP_MEMORY_SCOPE_AGENT); }

// ---------------------------------------------------------------- utilities
__global__ __launch_bounds__(256) void k_zero(unsigned int* p, int n) {
    int i = blockIdx.x * 256 + threadIdx.x;
    if (i < n) p[i] = 0u;
}

__global__ __launch_bounds__(256) void k_conv4(const float* __restrict__ in,
                                               unsigned short* __restrict__ out, int n4) {
    int i = blockIdx.x * 256 + threadIdx.x;
    if (i >= n4) return;
    float4 v = ((const float4*)in)[i];
    unsigned int w0 = (unsigned int)f2bf(v.x) | ((unsigned int)f2bf(v.y) << 16);
    unsigned int w1 = (unsigned int)f2bf(v.z) | ((unsigned int)f2bf(v.w) << 16);
    ((uint2*)(void*)out)[i] = make_uint2(w0, w1);
}

// hs: f32 -> bf16 (for pre-GEMM) + fp8 (for attention)
__global__ __launch_bounds__(256) void k_convhs(const float* __restrict__ in,
                                                unsigned short* __restrict__ obf,
                                                unsigned int* __restrict__ o8, int n4) {
    int i = blockIdx.x * 256 + threadIdx.x;
    if (i >= n4) return;
    float4 v = ((const float4*)in)[i];
    unsigned int w0 = (unsigned int)f2bf(v.x) | ((unsigned int)f2bf(v.y) << 16);
    unsigned int w1 = (unsigned int)f2bf(v.z) | ((unsigned int)f2bf(v.w) << 16);
    ((uint2*)(void*)obf)[i] = make_uint2(w0, w1);
    o8[i] = pack4fp8(v.x, v.y, v.z, v.w);
}

__global__ __launch_bounds__(256) void k_conv8(const float* __restrict__ in,
                                               unsigned int* __restrict__ o8, int n4) {
    int i = blockIdx.x * 256 + threadIdx.x;
    if (i >= n4) return;
    float4 v = ((const float4*)in)[i];
    o8[i] = pack4fp8(v.x, v.y, v.z, v.w);
}

// permuted fp8 cat: out row for gate-row n = ((n&1023)>>2)*16 + (n>>10)*4 + (n&3)
__global__ __launch_bounds__(256) void k_catp8(const float* __restrict__ A, const float* __restrict__ Bsrc,
                                               unsigned int* __restrict__ dst, int Ka, int Kb) {
    int idx = blockIdx.x * 256 + threadIdx.x;
    int K4 = (Ka + Kb) >> 2;
    if (idx >= 4096 * K4) return;
    int n = idx / K4, k4 = idx - n * K4, k = k4 * 4;
    const float* src = (k < Ka) ? (A + (size_t)n * Ka + k) : (Bsrc + (size_t)n * Kb + (k - Ka));
    int outrow = ((n & 1023) >> 2) * 16 + (n >> 10) * 4 + (n & 3);
    dst[(size_t)outrow * K4 + k4] = pack4fp8(src[0], src[1], src[2], src[3]);
}

__global__ __launch_bounds__(256) void k_woutpad(const float* __restrict__ W, unsigned short* __restrict__ dst) {
    int idx = blockIdx.x * 256 + threadIdx.x;
    if (idx >= 5120 * 2048) return;
    int n = idx >> 11, k = idx & 2047;
    dst[idx] = (n < 5000) ? f2bf(W[(size_t)n * 2048 + k]) : (unsigned short)0;
}

__global__ __launch_bounds__(256) void k_bsum(const float* a0, const float* b0, const float* a1, const float* b1,
                                              float* s0, float* s1) {
    int i = blockIdx.x * 256 + threadIdx.x;
    if (i < 4096) s0[i] = a0[i] + b0[i];
    else if (i < 8192) s1[i - 4096] = a1[i - 4096] + b1[i - 4096];
}

// eys fp8 [l][b][1024]
__global__ __launch_bounds__(256) void k_eys8(const float* __restrict__ embed, const int* __restrict__ ys_pad,
                                              unsigned int* __restrict__ eys8) {
    int idx = blockIdx.x * 256 + threadIdx.x;
    if (idx >= 3232 * 256) return;
    int rb = idx >> 8, c4 = idx & 255;
    int l = rb >> 5, b = rb & 31;
    int tok = (l == 0) ? 4999 : ys_pad[b * 100 + (l - 1)];
    const float* e = embed + (size_t)tok * 1024 + c4 * 4;
    eys8[idx] = pack4fp8(e[0], e[1], e[2], e[3]);
}

// dq init: z0=0 -> dq = tanh(bdec)
__global__ __launch_bounds__(256) void k_dq0(const float* __restrict__ bdec, unsigned short* __restrict__ dq) {
    int idx = blockIdx.x * 256 + threadIdx.x;
    if (idx >= 32768) return;
    dq[idx] = f2bf(tanhf(bdec[idx & 1023]));
}

// --------------------------------------------------- big 128x128 MFMA GEMM
// mode0: o8 = fp8(tanh(C+bias));  mode1: of32 = C
__global__ __launch_bounds__(256) void k_gemm128(
    const unsigned short* __restrict__ A, const unsigned short* __restrict__ B,
    int K, int N, const float* __restrict__ bias,
    unsigned char* __restrict__ o8, float* __restrict__ of32, int mode) {
    __shared__ uint4 Ab[512];
    __shared__ uint4 Bb[512];
    const int tid = threadIdx.x;
    const int lane = tid & 63, wave = tid >> 6;
    const int r = lane & 15, q = lane >> 4;
    const int wm = wave >> 1, wn = wave & 1;
    const size_t am0 = (size_t)blockIdx.y * 128;
    const size_t bn0 = (size_t)blockIdx.x * 128;
    floatx4 zf = {0.f, 0.f, 0.f, 0.f};
    floatx4 acc[4][4];
#pragma unroll
    for (int i = 0; i < 4; i++)
#pragma unroll
        for (int j = 0; j < 4; j++) acc[i][j] = zf;

    for (int k0 = 0; k0 < K; k0 += 32) {
        __syncthreads();
#pragma unroll
        for (int i = 0; i < 2; ++i) {
            int idx = i * 256 + tid;
            int qq = idx & 3, rr = idx >> 2;
            int slot = (rr >> 4) * 64 + ((qq << 4) | (rr & 15));
            Ab[slot] = *(const uint4*)(const void*)(A + (am0 + rr) * K + k0 + qq * 8);
            Bb[slot] = *(const uint4*)(const void*)(B + (bn0 + rr) * K + k0 + qq * 8);
        }
        __syncthreads();
        short8 af[4], bf[4];
#pragma unroll
        for (int t = 0; t < 4; t++) af[t] = *(const short8*)(const void*)&Ab[(wm * 4 + t) * 64 + lane];
#pragma unroll
        for (int t = 0; t < 4; t++) bf[t] = *(const short8*)(const void*)&Bb[(wn * 4 + t) * 64 + lane];
#pragma unroll
        for (int tm = 0; tm < 4; tm++)
#pragma unroll
            for (int tn = 0; tn < 4; tn++)
                acc[tm][tn] = __builtin_amdgcn_mfma_f32_16x16x32_bf16(af[tm], bf[tn], acc[tm][tn], 0, 0, 0);
    }
#pragma unroll
    for (int tm = 0; tm < 4; tm++) {
#pragma unroll
        for (int tn = 0; tn < 4; tn++) {
            int col = (int)bn0 + wn * 64 + tn * 16 + r;
#pragma unroll
            for (int reg = 0; reg < 4; ++reg) {
                size_t row = am0 + wm * 64 + tm * 16 + q * 4 + reg;
                float v = acc[tm][tn][reg];
                if (mode == 0) {
                    v = tanhf(v + bias[col]);
                    o8[row * (size_t)N + col] = f2fp8_1(v);
                } else {
                    of32[row * (size_t)N + col] = v;
                }
            }
        }
    }
}

// ------------------------------------------------- persistent scan kernel
struct SArgs {
    const unsigned char* pre8;   // [12800][1024] fp8
    const unsigned char* hs8;    // [12800][1024] fp8
    const unsigned char* eys8;   // [3232][1024] fp8
    const unsigned char* wc0p;   // [256*16][3072] fp8 (permuted rows)
    const unsigned char* wc1p;   // [256*16][2048] fp8 (permuted rows)
    const unsigned char* wdec;   // [1024][1024] fp8 (identity layout)
    unsigned short* dq;          // [32][1024] bf16
    unsigned char* attp;         // [32][1024] fp8
    unsigned char* z0p;          // [2][32][1024] fp8 (double-buffered)
    unsigned char* z1p;          // [2][32][1024] fp8 (double-buffered)
    unsigned short* zall;        // [3328][2048] bf16
    const float* bdec; const float* bs0; const float* bs1;
    float* part; float* lmaxg; float* lsumg;
    int* cntA; int* gcnt; int* gflag;
    const int* hlens;
};

// two-level tree barrier (R6-proven): 8 groups x 32 arrivals on separate
// 128B lines; group-last arrives at master; master-last publishes gflag.
DEV void gbar(int* gcnt, int* gflag, int ep, int grp) {
    __builtin_amdgcn_s_waitcnt(0);
    __syncthreads();
    if (threadIdx.x == 0) {
        int old = arrive(gcnt + grp * 32);
        if (old == ep * 32 - 1) {
            int o2 = arrive(gcnt + 256);
            if (o2 == ep * 8 - 1) {
                __hip_atomic_store(gflag, ep, __ATOMIC_RELAXED, __HIP_MEMORY_SCOPE_AGENT);
            }
        }
        while (__hip_atomic_load(gflag, __ATOMIC_RELAXED, __HIP_MEMORY_SCOPE_AGENT) < ep)
            __builtin_amdgcn_s_sleep(1);
    }
    __syncthreads();
}

__global__ __launch_bounds__(256, 1) void k_scan(SArgs a) {
    const int blk = blockIdx.x, tid = threadIdx.x;
    const int lane = tid & 63, wave = tid >> 6;
    const int b = blk >> 3, ch = blk & 7;       // attention role
    const int dc = blk;                          // cell role: d = dc*4..+3, 4 gates
    const int grp = blk & 7;
    const int r = lane & 15, q = lane >> 4;
    const int hlen = a.hlens[b];

    __shared__ __align__(16) unsigned char preS[51200];  // 50x1024 fp8 (whole slice)
    __shared__ __align__(16) unsigned char hsS[51200];   // 50x1024 fp8 (whole slice)
    __shared__ __align__(16) u64 dqStage[256];           // 2KB dq[b] stage
    __shared__ __align__(16) float redS[4][64][8];       // per-wave MFMA partials
    __shared__ float e4[50][4];
    __shared__ float es[52];
    __shared__ float ps[52];
    __shared__ float c0S[4][32], c1S[4][32];             // block-private cell state
    __shared__ unsigned char  z8tmp[128];
    __shared__ unsigned short z16tmp[128];
    __shared__ unsigned short dq16tmp[128];
    __shared__ int lastf;

    // one-time: pre8+hs8 slices -> LDS (plain loads; setup-written), c-state 0
    {
        const u64* psrc = (const u64*)(const void*)(a.pre8 + (size_t)(b * 400 + ch * 50) * 1024);
        const u64* hsrc = (const u64*)(const void*)(a.hs8 + (size_t)(b * 400 + ch * 50) * 1024);
        u64* pd = (u64*)(void*)preS;
        u64* hd = (u64*)(void*)hsS;
        for (int i = tid; i < 6400; i += 256) { pd[i] = psrc[i]; hd[i] = hsrc[i]; }
        if (tid < 128) { c0S[tid >> 5][tid & 31] = 0.f; c1S[tid >> 5][tid & 31] = 0.f; }
    }
    __syncthreads();

    int ep = 0;
    for (int l = 0; l < 101; ++l) {
        unsigned char* z0cur = a.z0p + (size_t)(l & 1) * 32768;
        unsigned char* z0prv = a.z0p + (size_t)((l + 1) & 1) * 32768;
        unsigned char* z1cur = a.z1p + (size_t)(l & 1) * 32768;
        unsigned char* z1prv = a.z1p + (size_t)((l + 1) & 1) * 32768;

        // ================= phase A: attention =================
        {
            // stage dq[b] (2 KB bf16) coalesced
            dqStage[tid] = lda64((const char*)(const void*)a.dq + (size_t)b * 2048 + tid * 8);
            __syncthreads();
            float dqf[16];
            {
                const unsigned int* dw = (const unsigned int*)(const void*)dqStage + lane * 8;
#pragma unroll
                for (int i = 0; i < 8; ++i) {
                    unsigned int w = dw[i];
                    dqf[2 * i] = bf2f(w & 0xffffu);
                    dqf[2 * i + 1] = bf2f(w >> 16);
                }
            }
            for (int tl = wave; tl < 50; tl += 4) {
                uint4 v = *(const uint4*)(const void*)(preS + tl * 1024 + lane * 16);
                float x[16];
                un4(v.x, x); un4(v.y, x + 4); un4(v.z, x + 8); un4(v.w, x + 12);
                float s = 0.f;
#pragma unroll
                for (int i = 0; i < 16; ++i) s += x[i] * dqf[i];
                s += __shfl_xor(s, 1, 64);
                s += __shfl_xor(s, 2, 64);
                s += __shfl_xor(s, 4, 64);
                s += __shfl_xor(s, 8, 64);
                if ((lane & 15) == 0) e4[tl][lane >> 4] = s;
            }
            __syncthreads();
            if (tid < 50) {
                float4 v = *(const float4*)(const void*)e4[tid];
                float e = v.x + v.y + v.z + v.w;
                int t = ch * 50 + tid;
                es[tid] = (t < hlen) ? 2.0f * e : -1e30f;
            }
            __syncthreads();
            float lmax = -1e30f;
#pragma unroll
            for (int i = 0; i < 50; ++i) lmax = fmaxf(lmax, es[i]);
            if (tid < 50) ps[tid] = (es[tid] > -5e29f) ? __expf(es[tid] - lmax) : 0.f;
            __syncthreads();
            if (tid == 0) {
                float ssum = 0.f;
                for (int i = 0; i < 50; ++i) ssum += ps[i];
                staf(a.lmaxg + b * 8 + ch, lmax);
                staf(a.lsumg + b * 8 + ch, ssum);
            }
            const int c = tid * 4;
            float a0 = 0.f, a1 = 0.f, a2 = 0.f, a3 = 0.f;
            for (int tl = 0; tl < 50; ++tl) {
                float p = ps[tl];
                unsigned int h = *(const unsigned int*)(const void*)(hsS + tl * 1024 + c);
                float x[4];
                un4(h, x);
                a0 += p * x[0]; a1 += p * x[1]; a2 += p * x[2]; a3 += p * x[3];
            }
            {
                float* pb = a.part + ((size_t)(b * 8 + ch)) * 1024 + c;
                union { float f[2]; u64 q; } p0, p1;
                p0.f[0] = a0; p0.f[1] = a1; p1.f[0] = a2; p1.f[1] = a3;
                sta64(pb, p0.q); sta64(pb + 2, p1.q);
            }
            __builtin_amdgcn_s_waitcnt(0);
            __syncthreads();
            if (tid == 0) lastf = (arrive(a.cntA + b * 32) == 8 * l + 7);
            __syncthreads();
            if (lastf) {
                float lm[8], ls[8];
#pragma unroll
                for (int i = 0; i < 8; ++i) {
                    lm[i] = ldaf(a.lmaxg + b * 8 + i);
                    ls[i] = ldaf(a.lsumg + b * 8 + i);
                }
                float gm = -1e30f;
#pragma unroll
                for (int i = 0; i < 8; ++i) gm = fmaxf(gm, lm[i]);
                float Zs = 0.f;
#pragma unroll
                for (int i = 0; i < 8; ++i) Zs += ls[i] * __expf(lm[i] - gm);
                const float inv = 1.0f / Zs;
                float o0 = 0.f, o1 = 0.f, o2 = 0.f, o3 = 0.f;
#pragma unroll
                for (int i = 0; i < 8; ++i) {
                    float coef = __expf(lm[i] - gm) * inv;
                    const float* qp = a.part + ((size_t)(b * 8 + i)) * 1024 + c;
                    union { u64 q; float f[2]; } u0, u1;
                    u0.q = lda64(qp); u1.q = lda64(qp + 2);
                    o0 += coef * u0.f[0]; o1 += coef * u0.f[1];
                    o2 += coef * u1.f[0]; o3 += coef * u1.f[1];
                }
                sta32(a.attp + (size_t)b * 1024 + c, pack4fp8(o0, o1, o2, o3));
                sta64(a.zall + ((size_t)(l * 32 + b)) * 2048 + 1024 + c, pack4bf16(o0, o1, o2, o3));
            }
        }
        gbar(a.gcnt, a.gflag, ++ep, grp);

        // ================= phase B: LSTM cell 0 (full K=3072, direct operands) =====
        {
            const unsigned char* Br = a.wc0p + ((size_t)(dc * 16 + r)) * 3072 + wave * 256 + q * 8;
            const char* eyb  = (const char*)(const void*)a.eys8 + (size_t)l * 32768 + r * 1024 + wave * 256 + q * 8;
            const char* attb = (const char*)(const void*)a.attp + (size_t)r * 1024 + wave * 256 + q * 8;
            const char* z0b  = (const char*)(const void*)z0prv + (size_t)r * 1024 + wave * 256 + q * 8;
            floatx4 acc0 = {0.f, 0.f, 0.f, 0.f}, acc1 = acc0;
            // source 0: ey (plain loads, L2)
#pragma unroll
            for (int kk = 0; kk < 256; kk += 32) {
                long long bfr = *(const long long*)(const void*)(Br + kk);
                long long a0 = *(const long long*)(const void*)(eyb + kk);
                long long a1 = *(const long long*)(const void*)(eyb + 16384 + kk);
                acc0 = __builtin_amdgcn_mfma_f32_16x16x32_fp8_fp8(a0, bfr, acc0, 0, 0, 0);
                acc1 = __builtin_amdgcn_mfma_f32_16x16x32_fp8_fp8(a1, bfr, acc1, 0, 0, 0);
            }
            // source 1: att (agent loads)
#pragma unroll
            for (int kk = 0; kk < 256; kk += 32) {
                long long bfr = *(const long long*)(const void*)(Br + 1024 + kk);
                long long a0 = (long long)lda64(attb + kk);
                long long a1 = (long long)lda64(attb + 16384 + kk);
                acc0 = __builtin_amdgcn_mfma_f32_16x16x32_fp8_fp8(a0, bfr, acc0, 0, 0, 0);
                acc1 = __builtin_amdgcn_mfma_f32_16x16x32_fp8_fp8(a1, bfr, acc1, 0, 0, 0);
            }
            // source 2: z0prev (agent loads)
#pragma unroll
            for (int kk = 0; kk < 256; kk += 32) {
                long long bfr = *(const long long*)(const void*)(Br + 2048 + kk);
                long long a0 = (long long)lda64(z0b + kk);
                long long a1 = (long long)lda64(z0b + 16384 + kk);
                acc0 = __builtin_amdgcn_mfma_f32_16x16x32_fp8_fp8(a0, bfr, acc0, 0, 0, 0);
                acc1 = __builtin_amdgcn_mfma_f32_16x16x32_fp8_fp8(a1, bfr, acc1, 0, 0, 0);
            }
            *(floatx4*)(void*)&redS[wave][lane][0] = acc0;
            *(floatx4*)(void*)&redS[wave][lane][4] = acc1;
            __syncthreads();
            if (tid < 128) {
                const int bb = tid & 31, j = tid >> 5;
                const int qp = (bb & 15) >> 2;
                const int slot = (bb & 3) + ((bb >> 4) << 2);
                float g[4];
#pragma unroll
                for (int gg = 0; gg < 4; ++gg) {
                    const int lp = (qp << 4) | (gg * 4 + j);
                    g[gg] = redS[0][lp][slot] + redS[1][lp][slot] + redS[2][lp][slot] + redS[3][lp][slot]
                          + a.bs0[gg * 1024 + dc * 4 + j];
                }
                float cn = sigm(g[1]) * c0S[j][bb] + sigm(g[0]) * tanhf(g[2]);
                c0S[j][bb] = cn;
                float z = sigm(g[3]) * tanhf(cn);
                z8tmp[bb * 4 + j] = f2fp8_1(z);
            }
            __syncthreads();
            if (tid < 32) {
                unsigned int w = *(const unsigned int*)(const void*)&z8tmp[tid * 4];
                sta32(z0cur + (size_t)tid * 1024 + dc * 4, w);
            }
        }
        gbar(a.gcnt, a.gflag, ++ep, grp);

        // ================= phase C: LSTM cell 1 (full K=2048) + dq ==============
        {
            // gates: sources z0cur | z1prv (agent loads)
            {
                const unsigned char* Br = a.wc1p + ((size_t)(dc * 16 + r)) * 2048 + wave * 256 + q * 8;
                const char* z0b = (const char*)(const void*)z0cur + (size_t)r * 1024 + wave * 256 + q * 8;
                const char* z1b = (const char*)(const void*)z1prv + (size_t)r * 1024 + wave * 256 + q * 8;
                floatx4 acc0 = {0.f, 0.f, 0.f, 0.f}, acc1 = acc0;
#pragma unroll
                for (int kk = 0; kk < 256; kk += 32) {
                    long long bfr = *(const long long*)(const void*)(Br + kk);
                    long long a0 = (long long)lda64(z0b + kk);
                    long long a1 = (long long)lda64(z0b + 16384 + kk);
                    acc0 = __builtin_amdgcn_mfma_f32_16x16x32_fp8_fp8(a0, bfr, acc0, 0, 0, 0);
                    acc1 = __builtin_amdgcn_mfma_f32_16x16x32_fp8_fp8(a1, bfr, acc1, 0, 0, 0);
                }
#pragma unroll
                for (int kk = 0; kk < 256; kk += 32) {
                    long long bfr = *(const long long*)(const void*)(Br + 1024 + kk);
                    long long a0 = (long long)lda64(z1b + kk);
                    long long a1 = (long long)lda64(z1b + 16384 + kk);
                    acc0 = __builtin_amdgcn_mfma_f32_16x16x32_fp8_fp8(a0, bfr, acc0, 0, 0, 0);
                    acc1 = __builtin_amdgcn_mfma_f32_16x16x32_fp8_fp8(a1, bfr, acc1, 0, 0, 0);
                }
                *(floatx4*)(void*)&redS[wave][lane][0] = acc0;
                *(floatx4*)(void*)&redS[wave][lane][4] = acc1;
            }
            __syncthreads();
            if (tid < 128) {
                const int bb = tid & 31, j = tid >> 5;
                const int qp = (bb & 15) >> 2;
                const int slot = (bb & 3) + ((bb >> 4) << 2);
                float g[4];
#pragma unroll
                for (int gg = 0; gg < 4; ++gg) {
                    const int lp = (qp << 4) | (gg * 4 + j);
                    g[gg] = redS[0][lp][slot] + redS[1][lp][slot] + redS[2][lp][slot] + redS[3][lp][slot]
                          + a.bs1[gg * 1024 + dc * 4 + j];
                }
                float cn = sigm(g[1]) * c1S[j][bb] + sigm(g[0]) * tanhf(g[2]);
                c1S[j][bb] = cn;
                float z = sigm(g[3]) * tanhf(cn);
                z8tmp[bb * 4 + j] = f2fp8_1(z);
                z16tmp[bb * 4 + j] = f2bf(z);
            }
            __syncthreads();   // redS reuse guard
            // dq = tanh(Wdec z0 + bdec), rows dc*4..+3 (K=1024; z0cur agent)
            {
                const unsigned char* Bd = a.wdec + ((size_t)(dc * 4 + (r & 3))) * 1024 + wave * 256 + q * 8;
                const char* D0 = (const char*)(const void*)z0cur + (size_t)r * 1024 + wave * 256 + q * 8;
                floatx4 acc0 = {0.f, 0.f, 0.f, 0.f}, acc1 = acc0;
#pragma unroll
                for (int kk = 0; kk < 256; kk += 32) {
                    long long bfr = *(const long long*)(const void*)(Bd + kk);
                    long long a0 = (long long)lda64(D0 + kk);
                    long long a1 = (long long)lda64(D0 + 16384 + kk);
                    acc0 = __builtin_amdgcn_mfma_f32_16x16x32_fp8_fp8(a0, bfr, acc0, 0, 0, 0);
                    acc1 = __builtin_amdgcn_mfma_f32_16x16x32_fp8_fp8(a1, bfr, acc1, 0, 0, 0);
                }
                *(floatx4*)(void*)&redS[wave][lane][0] = acc0;
                *(floatx4*)(void*)&redS[wave][lane][4] = acc1;
            }
            __syncthreads();
            if (tid < 128) {
                const int bb = tid & 31, j = tid >> 5;
                const int qp = (bb & 15) >> 2;
                const int slot = (bb & 3) + ((bb >> 4) << 2);
                const int lp = (qp << 4) | j;   // cols 4..15 are duplicates
                float s = redS[0][lp][slot] + redS[1][lp][slot] + redS[2][lp][slot] + redS[3][lp][slot];
                dq16tmp[bb * 4 + j] = f2bf(tanhf(s + a.bdec[dc * 4 + j]));
            }
            __syncthreads();
            if (tid < 32) {
                unsigned int wz = *(const unsigned int*)(const void*)&z8tmp[tid * 4];
                sta32(z1cur + (size_t)tid * 1024 + dc * 4, wz);
                u64 wq = *(const u64*)(const void*)&z16tmp[tid * 4];
                sta64(a.zall + ((size_t)(l * 32 + tid)) * 2048 + dc * 4, wq);
                u64 wd = *(const u64*)(const void*)&dq16tmp[tid * 4];
                sta64((char*)(void*)a.dq + (size_t)tid * 2048 + dc * 8, wd);
            }
        }
        gbar(a.gcnt, a.gflag, ++ep, grp);
    }
}

// ----------------------------------------------------------- CE reduction
__global__ __launch_bounds__(256) void k_ce(const float* __restrict__ y, const float* __restrict__ bout,
                                            const int* __restrict__ ys_pad, float* __restrict__ out) {
    const int rrow = blockIdx.x;
    const int l = rrow >> 5, b = rrow & 31;
    const float* yp = y + (size_t)rrow * 5120;
    const int tid = threadIdx.x;
    __shared__ float red[256];
    float m = -1e30f;
    for (int c = tid; c < 5000; c += 256) m = fmaxf(m, yp[c] + bout[c]);
    red[tid] = m; __syncthreads();
    for (int s = 128; s; s >>= 1) { if (tid < s) red[tid] = fmaxf(red[tid], red[tid + s]); __syncthreads(); }
    const float gmax = red[0]; __syncthreads();
    float ss = 0.f;
    for (int c = tid; c < 5000; c += 256) ss += __expf(yp[c] + bout[c] - gmax);
    red[tid] = ss; __syncthreads();
    for (int s = 128; s; s >>= 1) { if (tid < s) red[tid] += red[tid + s]; __syncthreads(); }
    if (tid == 0) {
        const int tgt = (l < 100) ? ys_pad[b * 100 + l] : 4999;
        const float lt = yp[tgt] + bout[tgt];
        const float ce = logf(red[0]) + gmax - lt;
        atomicAdd(out, ce * (100.0f / 3232.0f));
    }
}

// ---------------------------------------------------------------------------
extern "C" void kernel_launch(void* const* d_in, const int* in_sizes, int n_in,
                              void* d_out, int out_size, void* d_ws, size_t ws_size,
                              hipStream_t stream) {
    const float* hs_pad = (const float*)d_in[0];
    const float* embed  = (const float*)d_in[1];
    const float* Wenc   = (const float*)d_in[2];
    const float* benc   = (const float*)d_in[3];
    const float* Wdec   = (const float*)d_in[4];
    const float* bdec   = (const float*)d_in[5];
    const float* W_ih0  = (const float*)d_in[6];
    const float* W_hh0  = (const float*)d_in[7];
    const float* b_ih0  = (const float*)d_in[8];
    const float* b_hh0  = (const float*)d_in[9];
    const float* W_ih1  = (const float*)d_in[10];
    const float* W_hh1  = (const float*)d_in[11];
    const float* b_ih1  = (const float*)d_in[12];
    const float* b_hh1  = (const float*)d_in[13];
    const float* Wout   = (const float*)d_in[14];
    const float* bout   = (const float*)d_in[15];
    const int*   hlens  = (const int*)d_in[16];
    const int*   ys_pad = (const int*)d_in[17];
    float* out = (float*)d_out;
    uint8_t* ws = (uint8_t*)d_ws;

    // layout: dead-by-final-GEMM buffers first (Y f32 68.2MB aliases them)
    constexpr size_t OFF_HS    = 0;                        // 26,214,400 bf16 hs (dead after pre-GEMM)
    constexpr size_t OFF_PRE8  = OFF_HS    + 26214400;     // 13,107,200
    constexpr size_t OFF_HS8   = OFF_PRE8  + 13107200;     // 13,107,200
    constexpr size_t OFF_WC0P  = OFF_HS8   + 13107200;     // 12,582,912
    constexpr size_t OFF_WC1P  = OFF_WC0P  + 12582912;     //  8,388,608
    constexpr size_t OFF_WDEC8 = OFF_WC1P  + 8388608;      //  1,048,576
    constexpr size_t OFF_WENC  = OFF_WDEC8 + 1048576;      //  2,097,152 bf16
    constexpr size_t OFF_EYS8  = OFF_WENC  + 2097152;      //  3,309,568
    constexpr size_t OFF_ZALL  = OFF_EYS8  + 3309568;      // 13,631,488 bf16 (survives final GEMM)
    constexpr size_t OFF_WOUT  = OFF_ZALL  + 13631488;     // 20,971,520 bf16 (survives)
    constexpr size_t OFF_PART  = OFF_WOUT  + 20971520;     //  1,048,576
    constexpr size_t OFF_DQP   = OFF_PART  + 1048576;      //  65,536 bf16
    constexpr size_t OFF_ATTP  = OFF_DQP   + 65536;        //  32,768
    constexpr size_t OFF_Z0P   = OFF_ATTP  + 32768;        //  65,536 (x2 buffers)
    constexpr size_t OFF_Z1P   = OFF_Z0P   + 65536;        //  65,536
    constexpr size_t OFF_LMAX  = OFF_Z1P   + 65536;        //  1,024
    constexpr size_t OFF_LSUM  = OFF_LMAX  + 1024;         //  1,024
    constexpr size_t OFF_BS0   = OFF_LSUM  + 1024;         //  16,384
    constexpr size_t OFF_BS1   = OFF_BS0   + 16384;        //  16,384
    constexpr size_t OFF_CNT   = OFF_BS1   + 16384;        //  8,192
    constexpr size_t OFF_Y     = 0;

    unsigned short* HS    = (unsigned short*)(ws + OFF_HS);
    unsigned char*  PRE8  = (unsigned char*)(ws + OFF_PRE8);
    unsigned char*  HS8   = (unsigned char*)(ws + OFF_HS8);
    unsigned char*  WC0P  = (unsigned char*)(ws + OFF_WC0P);
    unsigned char*  WC1P  = (unsigned char*)(ws + OFF_WC1P);
    unsigned char*  WDEC8 = (unsigned char*)(ws + OFF_WDEC8);
    unsigned short* WENC  = (unsigned short*)(ws + OFF_WENC);
    unsigned char*  EYS8  = (unsigned char*)(ws + OFF_EYS8);
    unsigned short* ZALL  = (unsigned short*)(ws + OFF_ZALL);
    unsigned short* WOUTP = (unsigned short*)(ws + OFF_WOUT);
    float* PART  = (float*)(ws + OFF_PART);
    unsigned short* DQP = (unsigned short*)(ws + OFF_DQP);
    unsigned char*  ATTP = (unsigned char*)(ws + OFF_ATTP);
    unsigned char*  Z0P = (unsigned char*)(ws + OFF_Z0P);
    unsigned char*  Z1P = (unsigned char*)(ws + OFF_Z1P);
    float* LMAX  = (float*)(ws + OFF_LMAX);
    float* LSUM  = (float*)(ws + OFF_LSUM);
    float* BS0  = (float*)(ws + OFF_BS0);
    float* BS1  = (float*)(ws + OFF_BS1);
    int* CNT    = (int*)(ws + OFF_CNT);
    float* Y = (float*)(ws + OFF_Y);

    auto Zr = [&](void* p, int n_u32) {
        k_zero<<<dim3((n_u32 + 255) / 256), dim3(256), 0, stream>>>((unsigned int*)p, n_u32);
    };

    // ---- setup (re-done every call)
    Zr(Z0P, 16384);
    Zr(Z1P, 16384);
    Zr(CNT, 2048);
    Zr(d_out, 1);
    Zr(ZALL + (size_t)3232 * 2048, 98304);   // zall pad rows

    k_convhs<<<dim3(12800), dim3(256), 0, stream>>>(hs_pad, HS, (unsigned int*)(void*)HS8, 3276800);
    k_conv4<<<dim3(1024),  dim3(256), 0, stream>>>(Wenc, WENC, 262144);
    k_conv8<<<dim3(1024),  dim3(256), 0, stream>>>(Wdec, (unsigned int*)(void*)WDEC8, 262144);
    k_catp8<<<dim3(12288), dim3(256), 0, stream>>>(W_ih0, W_hh0, (unsigned int*)(void*)WC0P, 2048, 1024);
    k_catp8<<<dim3(8192),  dim3(256), 0, stream>>>(W_ih1, W_hh1, (unsigned int*)(void*)WC1P, 1024, 1024);
    k_woutpad<<<dim3(40960), dim3(256), 0, stream>>>(Wout, WOUTP);
    k_bsum<<<dim3(32), dim3(256), 0, stream>>>(b_ih0, b_hh0, b_ih1, b_hh1, BS0, BS1);
    k_eys8<<<dim3(3232), dim3(256), 0, stream>>>(embed, ys_pad, (unsigned int*)(void*)EYS8);

    // pre_enc = fp8(tanh(hs @ Wenc^T + benc))
    k_gemm128<<<dim3(8, 100), dim3(256), 0, stream>>>(HS, WENC, 1024, 1024, benc, PRE8, (float*)nullptr, 0);
    k_dq0<<<dim3(128), dim3(256), 0, stream>>>(bdec, DQP);

    // ---- the scan
    SArgs sa;
    sa.pre8 = PRE8; sa.hs8 = HS8; sa.eys8 = EYS8;
    sa.wc0p = WC0P; sa.wc1p = WC1P; sa.wdec = WDEC8;
    sa.dq = DQP; sa.attp = ATTP; sa.z0p = Z0P; sa.z1p = Z1P; sa.zall = ZALL;
    sa.bdec = bdec; sa.bs0 = BS0;  sa.bs1 = BS1;
    sa.part = PART; sa.lmaxg = LMAX; sa.lsumg = LSUM;
    sa.cntA = CNT;            // 32 counters, stride 32 ints
    sa.gcnt = CNT + 1024;     // 8 group counters (stride 32) + master at +256
    sa.gflag = CNT + 1536;    // isolated poll line
    sa.hlens = hlens;
    void* kp[] = { &sa };
    hipLaunchCooperativeKernel((const void*)k_scan, dim3(256), dim3(256), kp, 0, stream);

    // ---- output projection + CE
    k_gemm128<<<dim3(40, 26), dim3(256), 0, stream>>>(ZALL, WOUTP, 2048, 5120, (const float*)nullptr,
                                                      (unsigned char*)nullptr, Y, 1);
    k_ce<<<dim3(3232), dim3(256), 0, stream>>>(Y, bout, ys_pad, out);
}